// Round 1
// baseline (394.073 us; speedup 1.0000x reference)
//
#include <hip/hip_runtime.h>
#include <hip/hip_bf16.h>

constexpr int B_ = 4;
constexpr int L_ = 2048;
constexpr int D_ = 256;
constexpr int P_ = 32;
constexpr int TA = 8;    // tokens/block kernel A
constexpr int TC = 16;   // tokens/block kernel C
constexpr int TG = 16;   // tokens/block kernel G
constexpr int CL = 32;   // chunk length for KV scan
constexpr int NC = L_ / CL;  // 64 chunks

#define PI_F 3.14159265358979323846f
#define INV_SQRT_P 0.17677669529663687f  // 1/sqrt(32)

// ---------------- Kernel A: per-token small matmuls + values/gate ----------
// writes: m1c/m1s (pre-scan pos_cos*v1), qc/qs (query phasor), kc/ks (key
// phasor), gv (gated values), sg (store gate, pre-scan)
__global__ void kernelA(const float* __restrict__ x, const float* __restrict__ pos,
                        const float* __restrict__ w_mem1v, const float* __restrict__ b_mem1v,
                        const float* __restrict__ w_off, const float* __restrict__ b_off,
                        const float* __restrict__ w_key, const float* __restrict__ b_key,
                        const float* __restrict__ w_val, const float* __restrict__ b_val,
                        const float* __restrict__ w_gate, const float* __restrict__ b_gate,
                        float* __restrict__ m1c, float* __restrict__ m1s,
                        float* __restrict__ qc, float* __restrict__ qs,
                        float* __restrict__ kc, float* __restrict__ ks,
                        float* __restrict__ gv, float* __restrict__ sg) {
  __shared__ float xs[TA][D_];
  __shared__ float pp[TA][P_];
  __shared__ float gate[TA];
  int tid = threadIdx.x;
  int tok0 = blockIdx.x * TA;
  for (int i = tid; i < TA * D_; i += 256) {
    int t = i / D_, k = i % D_;
    xs[t][k] = x[(tok0 + t) * D_ + k];
  }
  for (int i = tid; i < TA * P_; i += 256) {
    int t = i / P_, j = i % P_;
    int l = (tok0 + t) % L_;
    pp[t][j] = pos[l * P_ + j];
  }
  __syncthreads();
  // gate (one thread per token)
  if (tid < TA) {
    float acc = b_gate[0];
    for (int k = 0; k < D_; ++k) acc += xs[tid][k] * w_gate[k];
    gate[tid] = 1.f / (1.f + expf(-acc));
    sg[tok0 + tid] = gate[tid];
  }
  // (token, p) role: v1, offset, key
  {
    int t = tid / P_, p = tid % P_;
    float a_v1 = b_mem1v[p], a_off = b_off[p], a_key = b_key[p];
    for (int k = 0; k < D_; ++k) {
      float xv = xs[t][k];
      a_v1 += xv * w_mem1v[k * P_ + p];
      a_off += xv * w_off[k * P_ + p];
      a_key += xv * w_key[k * P_ + p];
    }
    for (int j = 0; j < P_; ++j) a_off += pp[t][j] * w_off[(D_ + j) * P_ + p];
    float ph = pp[t][p];
    float pc = cosf(ph), ps = sinf(ph);
    int idx = (tok0 + t) * P_ + p;
    m1c[idx] = pc * a_v1;
    m1s[idx] = ps * a_v1;
    float off = tanhf(a_off) * PI_F;
    float oc = cosf(off), os = sinf(off);
    qc[idx] = pc * oc - ps * os;
    qs[idx] = ps * oc + pc * os;
    float kp = tanhf(a_key) * PI_F;
    kc[idx] = cosf(kp);
    ks[idx] = sinf(kp);
  }
  __syncthreads();
  // values role: thread = d
  {
    int d = tid;
    float acc[TA];
#pragma unroll
    for (int t = 0; t < TA; ++t) acc[t] = 0.f;
    for (int k = 0; k < D_; ++k) {
      float w = w_val[k * D_ + d];
#pragma unroll
      for (int t = 0; t < TA; ++t) acc[t] += xs[t][k] * w;
    }
    float bv = b_val[d];
#pragma unroll
    for (int t = 0; t < TA; ++t) {
      gv[(tok0 + t) * D_ + d] = (acc[t] + bv) * gate[t];
    }
  }
}

// ---------------- Scan kernel: inclusive scan along L per row --------------
// rows laid out base = (row/inner)*L*inner + row%inner, stride = inner
__global__ void scan_rows(const float* __restrict__ in, float* __restrict__ out,
                          int inner, int avg) {
  int row = blockIdx.x;
  int b = row / inner, r = row % inner;
  int base = b * L_ * inner + r;
  int tid = threadIdx.x, lane = tid & 63, wid = tid >> 6;
  __shared__ float wsum[4];
  float carry = 0.f;
  for (int t0 = 0; t0 < L_; t0 += 256) {
    int l = t0 + tid;
    float v = in[base + l * inner];
#pragma unroll
    for (int off = 1; off < 64; off <<= 1) {
      float n = __shfl_up(v, off, 64);
      if (lane >= off) v += n;
    }
    if (lane == 63) wsum[wid] = v;
    __syncthreads();
    float add = carry;
    for (int w = 0; w < wid; ++w) add += wsum[w];
    float res = v + add;
    out[base + l * inner] = avg ? res / (float)(l + 1) : res;
    carry += wsum[0] + wsum[1] + wsum[2] + wsum[3];
    __syncthreads();
  }
}

// ---------------- Kernel C: h = gelu([x,ctx]@w_sk1), storage phasors -------
__global__ void kernelC(const float* __restrict__ x, const float* __restrict__ ctx,
                        const float* __restrict__ w_sk1, const float* __restrict__ b_sk1,
                        const float* __restrict__ w_sk2, const float* __restrict__ b_sk2,
                        float* __restrict__ spc, float* __restrict__ sps) {
  __shared__ float xs[TC][D_];
  __shared__ float cs[TC][D_];
  __shared__ float hs[TC][D_];
  int tid = threadIdx.x;
  int tok0 = blockIdx.x * TC;
  for (int i = tid; i < TC * D_; i += 256) {
    int t = i / D_, k = i % D_;
    xs[t][k] = x[(tok0 + t) * D_ + k];
    cs[t][k] = ctx[(tok0 + t) * D_ + k];
  }
  __syncthreads();
  {
    int d = tid;
    float acc[TC];
    float bs = b_sk1[d];
#pragma unroll
    for (int t = 0; t < TC; ++t) acc[t] = bs;
    for (int k = 0; k < D_; ++k) {
      float w1 = w_sk1[k * D_ + d];
      float w2 = w_sk1[(D_ + k) * D_ + d];
#pragma unroll
      for (int t = 0; t < TC; ++t) acc[t] += xs[t][k] * w1 + cs[t][k] * w2;
    }
#pragma unroll
    for (int t = 0; t < TC; ++t) {
      float v = acc[t];
      hs[t][d] = 0.5f * v * (1.f + erff(v * 0.70710678118654752f));
    }
  }
  __syncthreads();
  for (int pass = 0; pass < 2; ++pass) {
    int t = pass * 8 + tid / P_;
    int p = tid % P_;
    float a = b_sk2[p];
    for (int k = 0; k < D_; ++k) a += hs[t][k] * w_sk2[k * P_ + p];
    float sp = tanhf(a) * PI_F;
    int idx = (tok0 + t) * P_ + p;
    spc[idx] = cosf(sp);
    sps[idx] = sinf(sp);
  }
}

// ---------------- Kernel D: per-chunk state sums ---------------------------
// U[b][c][path(cos=0,sin=1)][p][d]
__global__ void kernelD(const float* __restrict__ spc, const float* __restrict__ sps,
                        const float* __restrict__ gv, float* __restrict__ U) {
  int bc = blockIdx.x;
  int b = bc / NC, c = bc % NC;
  int tid = threadIdx.x;
  __shared__ float sc[CL][P_];
  __shared__ float ss[CL][P_];
  int lbase = b * L_ + c * CL;
  for (int i = tid; i < CL * P_; i += 256) {
    sc[i / P_][i % P_] = spc[lbase * P_ + i];
    ss[i / P_][i % P_] = sps[lbase * P_ + i];
  }
  __syncthreads();
  float ac[P_], as2[P_];
#pragma unroll
  for (int p = 0; p < P_; ++p) { ac[p] = 0.f; as2[p] = 0.f; }
  for (int t = 0; t < CL; ++t) {
    float g = gv[(lbase + t) * D_ + tid];
#pragma unroll
    for (int p = 0; p < P_; ++p) {
      ac[p] += sc[t][p] * g;
      as2[p] += ss[t][p] * g;
    }
  }
  int ub = (bc * 2 * P_) * D_ + tid;
#pragma unroll
  for (int p = 0; p < P_; ++p) {
    U[ub + p * D_] = ac[p];
    U[ub + (P_ + p) * D_] = as2[p];
  }
}

// ---------------- Kernel E: in-place exclusive prefix over chunks ----------
__global__ void kernelE(float* __restrict__ U) {
  int tid = blockIdx.x * 256 + threadIdx.x;  // B*2*P*D = 65536
  int d = tid % D_;
  int p = (tid / D_) % P_;
  int path = (tid / (D_ * P_)) % 2;
  int b = tid / (D_ * P_ * 2);
  int base = ((b * NC) * 2 * P_ + path * P_ + p) * D_ + d;
  const int cs = 2 * P_ * D_;
  float run = 0.f;
  for (int c0 = 0; c0 < NC; c0 += 8) {
    float v[8];
#pragma unroll
    for (int j = 0; j < 8; ++j) v[j] = U[base + (c0 + j) * cs];
#pragma unroll
    for (int j = 0; j < 8; ++j) {
      U[base + (c0 + j) * cs] = run;
      run += v[j];
    }
  }
}

// ---------------- Kernel F: within-chunk scan + retrieval ------------------
__global__ void kernelF(const float* __restrict__ U, const float* __restrict__ spc,
                        const float* __restrict__ sps, const float* __restrict__ kcg,
                        const float* __restrict__ ksg, const float* __restrict__ gv,
                        const float* __restrict__ sgc, float* __restrict__ kvr) {
  int bc = blockIdx.x;
  int b = bc / NC, c = bc % NC;
  int tid = threadIdx.x;
  __shared__ __align__(16) float q[CL][P_][4];
  __shared__ float scl[CL];
  int lbase = b * L_ + c * CL;
  for (int i = tid; i < CL * P_; i += 256) {
    int t = i / P_, p = i % P_;
    int gi = lbase * P_ + i;
    q[t][p][0] = spc[gi];
    q[t][p][1] = sps[gi];
    q[t][p][2] = kcg[gi];
    q[t][p][3] = ksg[gi];
  }
  if (tid < CL) {
    float g = sgc[lbase + tid];
    scl[tid] = rsqrtf(fmaxf(g, 1.f)) * INV_SQRT_P;
  }
  float Sc[P_], Ss[P_];
  int ub = (bc * 2 * P_) * D_ + tid;
#pragma unroll
  for (int p = 0; p < P_; ++p) {
    Sc[p] = U[ub + p * D_];
    Ss[p] = U[ub + (P_ + p) * D_];
  }
  __syncthreads();
  for (int t = 0; t < CL; ++t) {
    float g = gv[(lbase + t) * D_ + tid];
    float retc = 0.f, rets = 0.f;
#pragma unroll
    for (int p = 0; p < P_; ++p) {
      float4 v = *(const float4*)&q[t][p][0];
      Sc[p] += v.x * g;
      retc += v.z * Sc[p];
      Ss[p] += v.y * g;
      rets += v.w * Ss[p];
    }
    kvr[(lbase + t) * D_ + tid] = (retc + rets) * scl[t];
  }
}

// ---------------- Kernel G: pos_out + combine + LN + out matmul ------------
__global__ void kernelG(const float* __restrict__ x, const float* __restrict__ m1c,
                        const float* __restrict__ m1s, const float* __restrict__ qc,
                        const float* __restrict__ qs, const float* __restrict__ kvr,
                        const float* __restrict__ w_mem1o, const float* __restrict__ b_mem1o,
                        const float* __restrict__ ln_g, const float* __restrict__ ln_b,
                        const float* __restrict__ w_out, const float* __restrict__ b_out,
                        float* __restrict__ out) {
  __shared__ float pr[TG][P_];
  __shared__ float cb[TG][D_];
  __shared__ float mu_s[TG], rs_s[TG];
  int tid = threadIdx.x;
  int tok0 = blockIdx.x * TG;
  for (int pass = 0; pass < 2; ++pass) {
    int t = pass * 8 + tid / P_;
    int p = tid % P_;
    int idx = (tok0 + t) * P_ + p;
    pr[t][p] = (m1c[idx] * qc[idx] + m1s[idx] * qs[idx]) * INV_SQRT_P;
  }
  __syncthreads();
  int d = tid;
  {
    float accs[TG];
    float bm = b_mem1o[d];
#pragma unroll
    for (int t = 0; t < TG; ++t) accs[t] = bm;
    for (int p = 0; p < P_; ++p) {
      float w = w_mem1o[p * D_ + d];
#pragma unroll
      for (int t = 0; t < TG; ++t) accs[t] += pr[t][p] * w;
    }
#pragma unroll
    for (int t = 0; t < TG; ++t) cb[t][d] = accs[t] + kvr[(tok0 + t) * D_ + d];
  }
  __syncthreads();
  // LN stats: thread tid -> (t = tid/16, k-group = tid%16), shuffle-reduce
  {
    int t = tid >> 4, kg = tid & 15;
    float s = 0.f, s2 = 0.f;
#pragma unroll
    for (int i = 0; i < 16; ++i) {
      float v = cb[t][kg + 16 * i];
      s += v;
      s2 += v * v;
    }
#pragma unroll
    for (int m = 1; m < 16; m <<= 1) {
      s += __shfl_xor(s, m, 64);
      s2 += __shfl_xor(s2, m, 64);
    }
    if (kg == 0) {
      float mu = s / (float)D_;
      float var = s2 / (float)D_ - mu * mu;
      mu_s[t] = mu;
      rs_s[t] = rsqrtf(var + 1e-5f);
    }
  }
  __syncthreads();
  {
    float lg = ln_g[d], lb = ln_b[d];
#pragma unroll
    for (int t = 0; t < TG; ++t) cb[t][d] = (cb[t][d] - mu_s[t]) * rs_s[t] * lg + lb;
  }
  __syncthreads();
  {
    float acc[TG];
#pragma unroll
    for (int t = 0; t < TG; ++t) acc[t] = 0.f;
    for (int k = 0; k < D_; ++k) {
      float w = w_out[k * D_ + d];
#pragma unroll
      for (int t = 0; t < TG; ++t) acc[t] += cb[t][k] * w;
    }
    float bo = b_out[d];
#pragma unroll
    for (int t = 0; t < TG; ++t) {
      int idx = (tok0 + t) * D_ + d;
      out[idx] = x[idx] + acc[t] + bo;
    }
  }
}

extern "C" void kernel_launch(void* const* d_in, const int* in_sizes, int n_in,
                              void* d_out, int out_size, void* d_ws, size_t ws_size,
                              hipStream_t stream) {
  const float* x = (const float*)d_in[0];
  const float* pos = (const float*)d_in[1];
  const float* w_mem1v = (const float*)d_in[2];
  const float* b_mem1v = (const float*)d_in[3];
  const float* w_mem1o = (const float*)d_in[4];
  const float* b_mem1o = (const float*)d_in[5];
  const float* w_off = (const float*)d_in[6];
  const float* b_off = (const float*)d_in[7];
  const float* w_key = (const float*)d_in[8];
  const float* b_key = (const float*)d_in[9];
  const float* w_val = (const float*)d_in[10];
  const float* b_val = (const float*)d_in[11];
  const float* w_sk1 = (const float*)d_in[12];
  const float* b_sk1 = (const float*)d_in[13];
  const float* w_sk2 = (const float*)d_in[14];
  const float* b_sk2 = (const float*)d_in[15];
  const float* w_gate = (const float*)d_in[16];
  const float* b_gate = (const float*)d_in[17];
  const float* ln_g = (const float*)d_in[18];
  const float* ln_b = (const float*)d_in[19];
  const float* w_out = (const float*)d_in[20];
  const float* b_out = (const float*)d_in[21];
  float* out = (float*)d_out;
  float* ws = (float*)d_ws;

  const int BLP = B_ * L_ * P_;  // 262144
  const int BLD = B_ * L_ * D_;  // 2097152
  float* m1c = ws;
  float* m1s = m1c + BLP;
  float* qc = m1s + BLP;
  float* qs = qc + BLP;
  float* kc = qs + BLP;
  float* ks = kc + BLP;
  float* spc = ks + BLP;
  float* sps = spc + BLP;
  float* gv = sps + BLP;
  float* ctx = gv + BLD;   // reused as kvr after kernel C consumes it
  float* kvr = ctx;
  float* sg = ctx + BLD;
  float* U = sg + B_ * L_;
  // total: 8*BLP + 2*BLD + B_*L_ + B_*NC*2*P_*D_ floats  ~= 42 MB

  kernelA<<<(B_ * L_) / TA, 256, 0, stream>>>(x, pos, w_mem1v, b_mem1v, w_off, b_off,
                                              w_key, b_key, w_val, b_val, w_gate, b_gate,
                                              m1c, m1s, qc, qs, kc, ks, gv, sg);
  scan_rows<<<B_ * P_, 256, 0, stream>>>(m1c, m1c, P_, 0);
  scan_rows<<<B_ * P_, 256, 0, stream>>>(m1s, m1s, P_, 0);
  scan_rows<<<B_ * D_, 256, 0, stream>>>(x, ctx, D_, 1);
  scan_rows<<<B_, 256, 0, stream>>>(sg, sg, 1, 0);
  kernelC<<<(B_ * L_) / TC, 256, 0, stream>>>(x, ctx, w_sk1, b_sk1, w_sk2, b_sk2, spc, sps);
  kernelD<<<B_ * NC, 256, 0, stream>>>(spc, sps, gv, U);
  kernelE<<<(B_ * 2 * P_ * D_) / 256, 256, 0, stream>>>(U);
  kernelF<<<B_ * NC, 256, 0, stream>>>(U, spc, sps, kc, ks, gv, sg, kvr);
  kernelG<<<(B_ * L_) / TG, 256, 0, stream>>>(x, m1c, m1s, qc, qs, kvr, w_mem1o, b_mem1o,
                                              ln_g, ln_b, w_out, b_out, out);
}

// Round 2
// 331.788 us; speedup vs baseline: 1.1877x; 1.1877x over previous
//
#include <hip/hip_runtime.h>
#include <hip/hip_bf16.h>

constexpr int B_ = 4;
constexpr int L_ = 2048;
constexpr int D_ = 256;
constexpr int P_ = 32;
constexpr int TA = 8;    // tokens/block kernel A
constexpr int TG = 16;   // tokens/block kernel G
constexpr int CL = 32;   // chunk length for KV scan
constexpr int NC = L_ / CL;  // 64 chunks

#define PI_F 3.14159265358979323846f
#define INV_SQRT_P 0.17677669529663687f  // 1/sqrt(32)

typedef __attribute__((ext_vector_type(8))) short short8_t;
typedef __attribute__((ext_vector_type(4))) float floatx4;

static __device__ inline short f2bf(float f) {
  unsigned int u;
  __builtin_memcpy(&u, &f, 4);
  unsigned int r = (u + 0x7fffu + ((u >> 16) & 1u)) >> 16;
  return (short)r;
}
static __device__ inline float bf2f(short s) {
  unsigned int u = ((unsigned int)(unsigned short)s) << 16;
  float f;
  __builtin_memcpy(&f, &u, 4);
  return f;
}

// ---------------- Kernel A: per-token small matmuls + values/gate ----------
__global__ void kernelA(const float* __restrict__ x, const float* __restrict__ pos,
                        const float* __restrict__ w_mem1v, const float* __restrict__ b_mem1v,
                        const float* __restrict__ w_off, const float* __restrict__ b_off,
                        const float* __restrict__ w_key, const float* __restrict__ b_key,
                        const float* __restrict__ w_val, const float* __restrict__ b_val,
                        const float* __restrict__ w_gate, const float* __restrict__ b_gate,
                        float* __restrict__ m1c, float* __restrict__ m1s,
                        float* __restrict__ qc, float* __restrict__ qs,
                        float* __restrict__ kc, float* __restrict__ ks,
                        float* __restrict__ gv, float* __restrict__ sg) {
  __shared__ float xs[TA][D_];
  __shared__ float pp[TA][P_];
  __shared__ float gate[TA];
  int tid = threadIdx.x;
  int tok0 = blockIdx.x * TA;
  for (int i = tid; i < TA * D_; i += 256) {
    int t = i / D_, k = i % D_;
    xs[t][k] = x[(tok0 + t) * D_ + k];
  }
  for (int i = tid; i < TA * P_; i += 256) {
    int t = i / P_, j = i % P_;
    int l = (tok0 + t) % L_;
    pp[t][j] = pos[l * P_ + j];
  }
  __syncthreads();
  if (tid < TA) {
    float acc = b_gate[0];
    for (int k = 0; k < D_; ++k) acc += xs[tid][k] * w_gate[k];
    gate[tid] = 1.f / (1.f + expf(-acc));
    sg[tok0 + tid] = gate[tid];
  }
  {
    int t = tid / P_, p = tid % P_;
    float a_v1 = b_mem1v[p], a_off = b_off[p], a_key = b_key[p];
    for (int k = 0; k < D_; ++k) {
      float xv = xs[t][k];
      a_v1 += xv * w_mem1v[k * P_ + p];
      a_off += xv * w_off[k * P_ + p];
      a_key += xv * w_key[k * P_ + p];
    }
    for (int j = 0; j < P_; ++j) a_off += pp[t][j] * w_off[(D_ + j) * P_ + p];
    float ph = pp[t][p];
    float pc = cosf(ph), ps = sinf(ph);
    int idx = (tok0 + t) * P_ + p;
    m1c[idx] = pc * a_v1;
    m1s[idx] = ps * a_v1;
    float off = tanhf(a_off) * PI_F;
    float oc = cosf(off), os = sinf(off);
    qc[idx] = pc * oc - ps * os;
    qs[idx] = ps * oc + pc * os;
    float kp = tanhf(a_key) * PI_F;
    kc[idx] = cosf(kp);
    ks[idx] = sinf(kp);
  }
  __syncthreads();
  {
    int d = tid;
    float acc[TA];
#pragma unroll
    for (int t = 0; t < TA; ++t) acc[t] = 0.f;
    for (int k = 0; k < D_; ++k) {
      float w = w_val[k * D_ + d];
#pragma unroll
      for (int t = 0; t < TA; ++t) acc[t] += xs[t][k] * w;
    }
    float bv = b_val[d];
#pragma unroll
    for (int t = 0; t < TA; ++t) {
      gv[(tok0 + t) * D_ + d] = (acc[t] + bv) * gate[t];
    }
  }
}

// ---------------- Scan kernel: inclusive scan along L per row --------------
__global__ void scan_rows(const float* __restrict__ in, float* __restrict__ out,
                          int inner, int avg) {
  int row = blockIdx.x;
  int b = row / inner, r = row % inner;
  int base = b * L_ * inner + r;
  int tid = threadIdx.x, lane = tid & 63, wid = tid >> 6;
  __shared__ float wsum[4];
  float carry = 0.f;
  for (int t0 = 0; t0 < L_; t0 += 256) {
    int l = t0 + tid;
    float v = in[base + l * inner];
#pragma unroll
    for (int off = 1; off < 64; off <<= 1) {
      float n = __shfl_up(v, off, 64);
      if (lane >= off) v += n;
    }
    if (lane == 63) wsum[wid] = v;
    __syncthreads();
    float add = carry;
    for (int w = 0; w < wid; ++w) add += wsum[w];
    float res = v + add;
    out[base + l * inner] = avg ? res / (float)(l + 1) : res;
    carry += wsum[0] + wsum[1] + wsum[2] + wsum[3];
    __syncthreads();
  }
}

// ---------------- wcvt: w_sk1 [512,256] fp32 -> w1T [256,512] bf16 ---------
__global__ void wcvt(const float* __restrict__ w_sk1, short* __restrict__ w1T) {
  int idx = blockIdx.x * 256 + threadIdx.x;  // idx = n*512 + k
  int n = idx >> 9, k = idx & 511;
  w1T[idx] = f2bf(w_sk1[k * 256 + n]);
}

// ---------------- Kernel C2: hs = gelu([x,ctx]@w_sk1 + b) via bf16 MFMA ----
// grid: (M/64) x (N/64) = 128*4 = 512 blocks. Block: 4 waves, wave = 32x32
// C-macrotile of 2x2 16x16x32 MFMA frags. K=512 staged in LDS 128 at a time.
__global__ __launch_bounds__(256) void kernelC2(const float* __restrict__ x,
                                                const float* __restrict__ ctx,
                                                const short* __restrict__ w1T,
                                                const float* __restrict__ b_sk1,
                                                short* __restrict__ hs_bf) {
  __shared__ short As[64][136];  // pad to 136 bf16 (272B rows, 16B aligned)
  __shared__ short Bs[64][136];
  int tid = threadIdx.x;
  int mg = blockIdx.x >> 2, ng = blockIdx.x & 3;
  int tok0 = mg * 64, n0 = ng * 64;
  int lane = tid & 63, w = tid >> 6;
  int mw = (w & 1) * 32, nw = (w >> 1) * 32;

  floatx4 acc[2][2] = {{{0.f, 0.f, 0.f, 0.f}, {0.f, 0.f, 0.f, 0.f}},
                       {{0.f, 0.f, 0.f, 0.f}, {0.f, 0.f, 0.f, 0.f}}};
  int r = tid >> 5;    // 0..7 (staging row within pass)
  int c4 = tid & 31;   // vec4 column
  int ml = lane & 15, kq = (lane >> 4) * 8;

  for (int kt = 0; kt < 4; ++kt) {
    const float* srcA = (kt < 2 ? x : ctx);
    int koff = (kt & 1) * 128;
#pragma unroll
    for (int pass = 0; pass < 8; ++pass) {
      int row = pass * 8 + r;
      float4 v = *(const float4*)&srcA[(tok0 + row) * 256 + koff + c4 * 4];
      short4 o;
      o.x = f2bf(v.x); o.y = f2bf(v.y); o.z = f2bf(v.z); o.w = f2bf(v.w);
      *(short4*)&As[row][c4 * 4] = o;
      short4 b = *(const short4*)&w1T[(n0 + row) * 512 + kt * 128 + c4 * 4];
      *(short4*)&Bs[row][c4 * 4] = b;
    }
    __syncthreads();
#pragma unroll
    for (int s = 0; s < 4; ++s) {
      short8_t a0 = *(short8_t*)&As[mw + ml][s * 32 + kq];
      short8_t a1 = *(short8_t*)&As[mw + 16 + ml][s * 32 + kq];
      short8_t b0 = *(short8_t*)&Bs[nw + ml][s * 32 + kq];
      short8_t b1 = *(short8_t*)&Bs[nw + 16 + ml][s * 32 + kq];
      acc[0][0] = __builtin_amdgcn_mfma_f32_16x16x32_bf16(a0, b0, acc[0][0], 0, 0, 0);
      acc[0][1] = __builtin_amdgcn_mfma_f32_16x16x32_bf16(a0, b1, acc[0][1], 0, 0, 0);
      acc[1][0] = __builtin_amdgcn_mfma_f32_16x16x32_bf16(a1, b0, acc[1][0], 0, 0, 0);
      acc[1][1] = __builtin_amdgcn_mfma_f32_16x16x32_bf16(a1, b1, acc[1][1], 0, 0, 0);
    }
    __syncthreads();
  }
  // epilogue: bias + exact gelu, store bf16
  int col = lane & 15, rq = (lane >> 4) * 4;
#pragma unroll
  for (int nt = 0; nt < 2; ++nt) {
    int n = n0 + nw + nt * 16 + col;
    float bias = b_sk1[n];
#pragma unroll
    for (int mt = 0; mt < 2; ++mt) {
#pragma unroll
      for (int rg = 0; rg < 4; ++rg) {
        int tok = tok0 + mw + mt * 16 + rq + rg;
        float v = acc[mt][nt][rg] + bias;
        float g = 0.5f * v * (1.f + erff(v * 0.70710678118654752f));
        hs_bf[tok * 256 + n] = f2bf(g);
      }
    }
  }
}

// ---------------- Kernel C3: storage phases from hs (sk2, VALU) ------------
__global__ void kernelC3(const short* __restrict__ hs_bf, const float* __restrict__ w_sk2,
                         const float* __restrict__ b_sk2,
                         float* __restrict__ spc, float* __restrict__ sps) {
  __shared__ float hsl[16][256];
  int tid = threadIdx.x;
  int tok0 = blockIdx.x * 16;
  for (int i = tid; i < 16 * 64; i += 256) {
    int t = i >> 6, c = i & 63;
    short4 v = *(const short4*)&hs_bf[(tok0 + t) * 256 + c * 4];
    hsl[t][c * 4 + 0] = bf2f(v.x);
    hsl[t][c * 4 + 1] = bf2f(v.y);
    hsl[t][c * 4 + 2] = bf2f(v.z);
    hsl[t][c * 4 + 3] = bf2f(v.w);
  }
  __syncthreads();
  for (int pass = 0; pass < 2; ++pass) {
    int t = pass * 8 + tid / 32, p = tid % 32;
    float a = b_sk2[p];
    for (int k = 0; k < 256; ++k) a += hsl[t][k] * w_sk2[k * 32 + p];
    float sp = tanhf(a) * PI_F;
    int idx = (tok0 + t) * 32 + p;
    spc[idx] = cosf(sp);
    sps[idx] = sinf(sp);
  }
}

// ---------------- Kernel D: per-chunk state sums ---------------------------
__global__ void kernelD(const float* __restrict__ spc, const float* __restrict__ sps,
                        const float* __restrict__ gv, float* __restrict__ U) {
  int bc = blockIdx.x;
  int b = bc / NC, c = bc % NC;
  int tid = threadIdx.x;
  __shared__ float sc[CL][P_];
  __shared__ float ss[CL][P_];
  int lbase = b * L_ + c * CL;
  for (int i = tid; i < CL * P_; i += 256) {
    sc[i / P_][i % P_] = spc[lbase * P_ + i];
    ss[i / P_][i % P_] = sps[lbase * P_ + i];
  }
  __syncthreads();
  float ac[P_], as2[P_];
#pragma unroll
  for (int p = 0; p < P_; ++p) { ac[p] = 0.f; as2[p] = 0.f; }
  for (int t = 0; t < CL; ++t) {
    float g = gv[(lbase + t) * D_ + tid];
#pragma unroll
    for (int p = 0; p < P_; ++p) {
      ac[p] += sc[t][p] * g;
      as2[p] += ss[t][p] * g;
    }
  }
  int ub = (bc * 2 * P_) * D_ + tid;
#pragma unroll
  for (int p = 0; p < P_; ++p) {
    U[ub + p * D_] = ac[p];
    U[ub + (P_ + p) * D_] = as2[p];
  }
}

// ---------------- Kernel E: in-place exclusive prefix over chunks ----------
__global__ void kernelE(float* __restrict__ U) {
  int tid = blockIdx.x * 256 + threadIdx.x;  // B*2*P*D = 65536
  int d = tid % D_;
  int p = (tid / D_) % P_;
  int path = (tid / (D_ * P_)) % 2;
  int b = tid / (D_ * P_ * 2);
  int base = ((b * NC) * 2 * P_ + path * P_ + p) * D_ + d;
  const int cs = 2 * P_ * D_;
  float run = 0.f;
  for (int c0 = 0; c0 < NC; c0 += 8) {
    float v[8];
#pragma unroll
    for (int j = 0; j < 8; ++j) v[j] = U[base + (c0 + j) * cs];
#pragma unroll
    for (int j = 0; j < 8; ++j) {
      U[base + (c0 + j) * cs] = run;
      run += v[j];
    }
  }
}

// ---------------- Kernel F: within-chunk scan + retrieval ------------------
__global__ void kernelF(const float* __restrict__ U, const float* __restrict__ spc,
                        const float* __restrict__ sps, const float* __restrict__ kcg,
                        const float* __restrict__ ksg, const float* __restrict__ gv,
                        const float* __restrict__ sgc, float* __restrict__ kvr) {
  int bc = blockIdx.x;
  int b = bc / NC, c = bc % NC;
  int tid = threadIdx.x;
  __shared__ __align__(16) float q[CL][P_][4];
  __shared__ float scl[CL];
  int lbase = b * L_ + c * CL;
  for (int i = tid; i < CL * P_; i += 256) {
    int t = i / P_, p = i % P_;
    int gi = lbase * P_ + i;
    q[t][p][0] = spc[gi];
    q[t][p][1] = sps[gi];
    q[t][p][2] = kcg[gi];
    q[t][p][3] = ksg[gi];
  }
  if (tid < CL) {
    float g = sgc[lbase + tid];
    scl[tid] = rsqrtf(fmaxf(g, 1.f)) * INV_SQRT_P;
  }
  float Sc[P_], Ss[P_];
  int ub = (bc * 2 * P_) * D_ + tid;
#pragma unroll
  for (int p = 0; p < P_; ++p) {
    Sc[p] = U[ub + p * D_];
    Ss[p] = U[ub + (P_ + p) * D_];
  }
  __syncthreads();
  for (int t = 0; t < CL; ++t) {
    float g = gv[(lbase + t) * D_ + tid];
    float retc = 0.f, rets = 0.f;
#pragma unroll
    for (int p = 0; p < P_; ++p) {
      float4 v = *(const float4*)&q[t][p][0];
      Sc[p] += v.x * g;
      retc += v.z * Sc[p];
      Ss[p] += v.y * g;
      rets += v.w * Ss[p];
    }
    kvr[(lbase + t) * D_ + tid] = (retc + rets) * scl[t];
  }
}

// ---------------- Kernel G: pos_out + combine + LN + out matmul ------------
__global__ void kernelG(const float* __restrict__ x, const float* __restrict__ m1c,
                        const float* __restrict__ m1s, const float* __restrict__ qc,
                        const float* __restrict__ qs, const float* __restrict__ kvr,
                        const float* __restrict__ w_mem1o, const float* __restrict__ b_mem1o,
                        const float* __restrict__ ln_g, const float* __restrict__ ln_b,
                        const float* __restrict__ w_out, const float* __restrict__ b_out,
                        float* __restrict__ out) {
  __shared__ float pr[TG][P_];
  __shared__ float cb[TG][D_];
  __shared__ float mu_s[TG], rs_s[TG];
  int tid = threadIdx.x;
  int tok0 = blockIdx.x * TG;
  for (int pass = 0; pass < 2; ++pass) {
    int t = pass * 8 + tid / 32, p = tid % 32;
    int idx = (tok0 + t) * P_ + p;
    pr[t][p] = (m1c[idx] * qc[idx] + m1s[idx] * qs[idx]) * INV_SQRT_P;
  }
  __syncthreads();
  int d = tid;
  {
    float accs[TG];
    float bm = b_mem1o[d];
#pragma unroll
    for (int t = 0; t < TG; ++t) accs[t] = bm;
    for (int p = 0; p < P_; ++p) {
      float w = w_mem1o[p * D_ + d];
#pragma unroll
      for (int t = 0; t < TG; ++t) accs[t] += pr[t][p] * w;
    }
#pragma unroll
    for (int t = 0; t < TG; ++t) cb[t][d] = accs[t] + kvr[(tok0 + t) * D_ + d];
  }
  __syncthreads();
  {
    int t = tid >> 4, kg = tid & 15;
    float s = 0.f, s2 = 0.f;
#pragma unroll
    for (int i = 0; i < 16; ++i) {
      float v = cb[t][kg + 16 * i];
      s += v;
      s2 += v * v;
    }
#pragma unroll
    for (int m = 1; m < 16; m <<= 1) {
      s += __shfl_xor(s, m, 64);
      s2 += __shfl_xor(s2, m, 64);
    }
    if (kg == 0) {
      float mu = s / (float)D_;
      float var = s2 / (float)D_ - mu * mu;
      mu_s[t] = mu;
      rs_s[t] = rsqrtf(var + 1e-5f);
    }
  }
  __syncthreads();
  {
    float lg = ln_g[d], lb = ln_b[d];
#pragma unroll
    for (int t = 0; t < TG; ++t) cb[t][d] = (cb[t][d] - mu_s[t]) * rs_s[t] * lg + lb;
  }
  __syncthreads();
  {
    float acc[TG];
#pragma unroll
    for (int t = 0; t < TG; ++t) acc[t] = 0.f;
    for (int k = 0; k < D_; ++k) {
      float w = w_out[k * D_ + d];
#pragma unroll
      for (int t = 0; t < TG; ++t) acc[t] += cb[t][k] * w;
    }
    float bo = b_out[d];
#pragma unroll
    for (int t = 0; t < TG; ++t) {
      int idx = (tok0 + t) * D_ + d;
      out[idx] = x[idx] + acc[t] + bo;
    }
  }
}

extern "C" void kernel_launch(void* const* d_in, const int* in_sizes, int n_in,
                              void* d_out, int out_size, void* d_ws, size_t ws_size,
                              hipStream_t stream) {
  const float* x = (const float*)d_in[0];
  const float* pos = (const float*)d_in[1];
  const float* w_mem1v = (const float*)d_in[2];
  const float* b_mem1v = (const float*)d_in[3];
  const float* w_mem1o = (const float*)d_in[4];
  const float* b_mem1o = (const float*)d_in[5];
  const float* w_off = (const float*)d_in[6];
  const float* b_off = (const float*)d_in[7];
  const float* w_key = (const float*)d_in[8];
  const float* b_key = (const float*)d_in[9];
  const float* w_val = (const float*)d_in[10];
  const float* b_val = (const float*)d_in[11];
  const float* w_sk1 = (const float*)d_in[12];
  const float* b_sk1 = (const float*)d_in[13];
  const float* w_sk2 = (const float*)d_in[14];
  const float* b_sk2 = (const float*)d_in[15];
  const float* w_gate = (const float*)d_in[16];
  const float* b_gate = (const float*)d_in[17];
  const float* ln_g = (const float*)d_in[18];
  const float* ln_b = (const float*)d_in[19];
  const float* w_out = (const float*)d_in[20];
  const float* b_out = (const float*)d_in[21];
  float* out = (float*)d_out;
  float* ws = (float*)d_ws;

  const int BLP = B_ * L_ * P_;  // 262144
  const int BLD = B_ * L_ * D_;  // 2097152
  float* m1c = ws;
  float* m1s = m1c + BLP;
  float* qc = m1s + BLP;
  float* qs = qc + BLP;
  float* kc = qs + BLP;
  float* ks = kc + BLP;
  float* spc = ks + BLP;
  float* sps = spc + BLP;
  float* gv = sps + BLP;
  float* ctx = gv + BLD;   // reused as kvr after C2 consumes it
  float* kvr = ctx;
  float* sg = ctx + BLD;
  float* U = sg + B_ * L_;
  short* hs_bf = (short*)(U + (size_t)B_ * NC * 2 * P_ * D_);  // 8192*256 bf16
  short* w1T = hs_bf + (size_t)B_ * L_ * D_;                   // 256*512 bf16
  // total ~44.5 MB

  wcvt<<<512, 256, 0, stream>>>(w_sk1, w1T);
  kernelA<<<(B_ * L_) / TA, 256, 0, stream>>>(x, pos, w_mem1v, b_mem1v, w_off, b_off,
                                              w_key, b_key, w_val, b_val, w_gate, b_gate,
                                              m1c, m1s, qc, qs, kc, ks, gv, sg);
  scan_rows<<<B_ * P_, 256, 0, stream>>>(m1c, m1c, P_, 0);
  scan_rows<<<B_ * P_, 256, 0, stream>>>(m1s, m1s, P_, 0);
  scan_rows<<<B_ * D_, 256, 0, stream>>>(x, ctx, D_, 1);
  scan_rows<<<B_, 256, 0, stream>>>(sg, sg, 1, 0);
  kernelC2<<<512, 256, 0, stream>>>(x, ctx, w1T, b_sk1, hs_bf);
  kernelC3<<<(B_ * L_) / 16, 256, 0, stream>>>(hs_bf, w_sk2, b_sk2, spc, sps);
  kernelD<<<B_ * NC, 256, 0, stream>>>(spc, sps, gv, U);
  kernelE<<<(B_ * 2 * P_ * D_) / 256, 256, 0, stream>>>(U);
  kernelF<<<B_ * NC, 256, 0, stream>>>(U, spc, sps, kc, ks, gv, sg, kvr);
  kernelG<<<(B_ * L_) / TG, 256, 0, stream>>>(x, m1c, m1s, qc, qs, kvr, w_mem1o, b_mem1o,
                                              ln_g, ln_b, w_out, b_out, out);
}

// Round 3
// 262.838 us; speedup vs baseline: 1.4993x; 1.2623x over previous
//
#include <hip/hip_runtime.h>
#include <hip/hip_bf16.h>

constexpr int B_ = 4;
constexpr int L_ = 2048;
constexpr int D_ = 256;
constexpr int P_ = 32;
constexpr int TG = 16;   // tokens/block kernel G1
constexpr int CL = 32;   // chunk length for KV scan
constexpr int NC = L_ / CL;  // 64 chunks

#define PI_F 3.14159265358979323846f
#define INV_SQRT_P 0.17677669529663687f  // 1/sqrt(32)

typedef __attribute__((ext_vector_type(8))) short short8_t;
typedef __attribute__((ext_vector_type(4))) float floatx4;

static __device__ inline short f2bf(float f) {
  unsigned int u;
  __builtin_memcpy(&u, &f, 4);
  unsigned int r = (u + 0x7fffu + ((u >> 16) & 1u)) >> 16;
  return (short)r;
}
static __device__ inline float bf2f(short s) {
  unsigned int u = ((unsigned int)(unsigned short)s) << 16;
  float f;
  __builtin_memcpy(&f, &u, 4);
  return f;
}

// ---------------- wprep: all weight casts/transposes + x->bf16 + poff ------
// blocks [0,384): WA[n][k] = concat(w_val|w_mem1v|w_off_x|w_key|w_gate|0)^T
// blocks [384,896): W1[n][k] = w_sk1^T   (n<256, k<512)
// blocks [896,1152): WO[n][k] = w_out^T
// blocks [1152,3200): xbf = bf16(x), 4 elem/thread
// blocks [3200,3456): poff[l][p] = b_off[p] + pos[l]@w_off_pos[:,p]
__global__ void wprep(const float* __restrict__ x, const float* __restrict__ pos,
                      const float* __restrict__ w_val, const float* __restrict__ w_mem1v,
                      const float* __restrict__ w_off, const float* __restrict__ b_off,
                      const float* __restrict__ w_key, const float* __restrict__ w_gate,
                      const float* __restrict__ w_sk1, const float* __restrict__ w_out,
                      short* __restrict__ WA, short* __restrict__ W1,
                      short* __restrict__ WO, short* __restrict__ xbf,
                      float* __restrict__ poff) {
  int blk = blockIdx.x, tid = threadIdx.x;
  if (blk < 384) {
    int idx = blk * 256 + tid;
    int n = idx >> 8, k = idx & 255;
    float v;
    if (n < 256) v = w_val[k * 256 + n];
    else if (n < 288) v = w_mem1v[k * 32 + (n - 256)];
    else if (n < 320) v = w_off[k * 32 + (n - 288)];
    else if (n < 352) v = w_key[k * 32 + (n - 320)];
    else if (n == 352) v = w_gate[k];
    else v = 0.f;
    WA[idx] = f2bf(v);
  } else if (blk < 896) {
    int idx = (blk - 384) * 256 + tid;
    int n = idx >> 9, k = idx & 511;
    W1[idx] = f2bf(w_sk1[k * 256 + n]);
  } else if (blk < 1152) {
    int idx = (blk - 896) * 256 + tid;
    int n = idx >> 8, k = idx & 255;
    WO[idx] = f2bf(w_out[k * 256 + n]);
  } else if (blk < 3200) {
    int idx = ((blk - 1152) * 256 + tid) * 4;
    float4 v = *(const float4*)&x[idx];
    short4 o;
    o.x = f2bf(v.x); o.y = f2bf(v.y); o.z = f2bf(v.z); o.w = f2bf(v.w);
    *(short4*)&xbf[idx] = o;
  } else {
    int idx = (blk - 3200) * 256 + tid;
    int l = idx >> 5, p = idx & 31;
    float a = b_off[p];
    for (int j = 0; j < 32; ++j) a += pos[l * 32 + j] * w_off[(256 + j) * 32 + p];
    poff[idx] = a;
  }
}

// ---------------- generic bf16 MFMA GEMM, 64x64 tile -----------------------
// MODE 0: Y[8192,384] fp32 = A0 @ W (no bias)        KTILES=2 NBLK=6
// MODE 1: hs bf16 = gelu(A @ W + bias), A = [A0|A1]  KTILES=4 NBLK=4
// MODE 2: out fp32 = xres + A0 @ W + bias            KTILES=2 NBLK=4
template <int KTILES, int NBLK, int MODE>
__global__ __launch_bounds__(256) void gemm_k(const short* __restrict__ A0,
                                              const short* __restrict__ A1,
                                              const short* __restrict__ W,
                                              const float* __restrict__ bias,
                                              const float* __restrict__ xres,
                                              float* __restrict__ outf,
                                              short* __restrict__ outb) {
  __shared__ short As[64][136];
  __shared__ short Bs[64][136];
  int tid = threadIdx.x;
  int mg = blockIdx.x / NBLK, ng = blockIdx.x % NBLK;
  int tok0 = mg * 64, n0 = ng * 64;
  int lane = tid & 63, w = tid >> 6;
  int mw = (w & 1) * 32, nw = (w >> 1) * 32;
  floatx4 acc[2][2] = {{{0.f, 0.f, 0.f, 0.f}, {0.f, 0.f, 0.f, 0.f}},
                       {{0.f, 0.f, 0.f, 0.f}, {0.f, 0.f, 0.f, 0.f}}};
  int r2 = tid >> 4, c8 = tid & 15;
  int ml = lane & 15, kq = (lane >> 4) * 8;
  const int K = KTILES * 128;

  for (int kt = 0; kt < KTILES; ++kt) {
    const short* Asrc;
    int cb;
    if (KTILES == 4) {
      Asrc = (kt < 2) ? A0 : A1;
      cb = (kt & 1) * 128;
    } else {
      Asrc = A0;
      cb = kt * 128;
    }
#pragma unroll
    for (int pass = 0; pass < 4; ++pass) {
      int row = pass * 16 + r2;
      *(short8_t*)&As[row][c8 * 8] =
          *(const short8_t*)&Asrc[(tok0 + row) * 256 + cb + c8 * 8];
      *(short8_t*)&Bs[row][c8 * 8] =
          *(const short8_t*)&W[(n0 + row) * K + kt * 128 + c8 * 8];
    }
    __syncthreads();
#pragma unroll
    for (int s = 0; s < 4; ++s) {
      short8_t a0 = *(short8_t*)&As[mw + ml][s * 32 + kq];
      short8_t a1 = *(short8_t*)&As[mw + 16 + ml][s * 32 + kq];
      short8_t b0 = *(short8_t*)&Bs[nw + ml][s * 32 + kq];
      short8_t b1 = *(short8_t*)&Bs[nw + 16 + ml][s * 32 + kq];
      acc[0][0] = __builtin_amdgcn_mfma_f32_16x16x32_bf16(a0, b0, acc[0][0], 0, 0, 0);
      acc[0][1] = __builtin_amdgcn_mfma_f32_16x16x32_bf16(a0, b1, acc[0][1], 0, 0, 0);
      acc[1][0] = __builtin_amdgcn_mfma_f32_16x16x32_bf16(a1, b0, acc[1][0], 0, 0, 0);
      acc[1][1] = __builtin_amdgcn_mfma_f32_16x16x32_bf16(a1, b1, acc[1][1], 0, 0, 0);
    }
    __syncthreads();
  }
  int col = lane & 15, rq = (lane >> 4) * 4;
#pragma unroll
  for (int nt = 0; nt < 2; ++nt) {
    int n = n0 + nw + nt * 16 + col;
    float bv = (MODE == 0) ? 0.f : bias[n];
#pragma unroll
    for (int mt = 0; mt < 2; ++mt) {
#pragma unroll
      for (int rg = 0; rg < 4; ++rg) {
        int tok = tok0 + mw + mt * 16 + rq + rg;
        float v = acc[mt][nt][rg] + bv;
        if (MODE == 0) {
          outf[tok * 384 + n] = v;
        } else if (MODE == 1) {
          float g = 0.5f * v * (1.f + erff(v * 0.70710678118654752f));
          outb[tok * 256 + n] = f2bf(g);
        } else {
          outf[tok * 256 + n] = xres[tok * 256 + n] + v;
        }
      }
    }
  }
}

// ---------------- Kernel A3: elementwise phasor prep from Y ----------------
__global__ void kernelA3(const float* __restrict__ Y, const float* __restrict__ pos,
                         const float* __restrict__ poff, const float* __restrict__ b_mem1v,
                         const float* __restrict__ b_key, const float* __restrict__ b_gate,
                         const float* __restrict__ b_val,
                         float* __restrict__ m1c, float* __restrict__ m1s,
                         float* __restrict__ qc, float* __restrict__ qs,
                         float* __restrict__ kc, float* __restrict__ ks,
                         float* __restrict__ gv, float* __restrict__ sg) {
  __shared__ float gsh[8];
  int tid = threadIdx.x;
  int tok0 = blockIdx.x * 8;
  int t = tid >> 5, p = tid & 31;
  int tok = tok0 + t, l = tok & (L_ - 1);
  float gate = 1.f / (1.f + expf(-(Y[tok * 384 + 352] + b_gate[0])));
  if (p == 0) {
    sg[tok] = gate;
    gsh[t] = gate;
  }
  float v1 = Y[tok * 384 + 256 + p] + b_mem1v[p];
  float ph = pos[l * 32 + p];
  float pc = cosf(ph), ps = sinf(ph);
  int idx = tok * 32 + p;
  m1c[idx] = pc * v1;
  m1s[idx] = ps * v1;
  float off = tanhf(Y[tok * 384 + 288 + p] + poff[l * 32 + p]) * PI_F;
  float oc = cosf(off), os = sinf(off);
  qc[idx] = pc * oc - ps * os;
  qs[idx] = ps * oc + pc * os;
  float kp = tanhf(Y[tok * 384 + 320 + p] + b_key[p]) * PI_F;
  kc[idx] = cosf(kp);
  ks[idx] = sinf(kp);
  __syncthreads();
  for (int tt = 0; tt < 8; ++tt) {
    gv[(tok0 + tt) * 256 + tid] = (Y[(tok0 + tt) * 384 + tid] + b_val[tid]) * gsh[tt];
  }
}

// ---------------- scan2: inclusive scan along L for m1c and m1s ------------
__global__ void scan2(float* __restrict__ a, float* __restrict__ b2) {
  float* arr = (blockIdx.x < B_ * P_) ? a : b2;
  int row = blockIdx.x & (B_ * P_ - 1);
  int b = row / P_, r = row % P_;
  int base = b * L_ * P_ + r;
  int tid = threadIdx.x, lane = tid & 63, wid = tid >> 6;
  __shared__ float wsum[4];
  float carry = 0.f;
  for (int t0 = 0; t0 < L_; t0 += 256) {
    int l = t0 + tid;
    float v = arr[base + l * P_];
#pragma unroll
    for (int off = 1; off < 64; off <<= 1) {
      float n = __shfl_up(v, off, 64);
      if (lane >= off) v += n;
    }
    if (lane == 63) wsum[wid] = v;
    __syncthreads();
    float add = carry;
    for (int w = 0; w < wid; ++w) add += wsum[w];
    arr[base + l * P_] = v + add;
    carry += wsum[0] + wsum[1] + wsum[2] + wsum[3];
    __syncthreads();
  }
}

// ---------------- scan_rows: generic fp32 inclusive scan -------------------
__global__ void scan_rows(const float* __restrict__ in, float* __restrict__ out,
                          int inner) {
  int row = blockIdx.x;
  int b = row / inner, r = row % inner;
  int base = b * L_ * inner + r;
  int tid = threadIdx.x, lane = tid & 63, wid = tid >> 6;
  __shared__ float wsum[4];
  float carry = 0.f;
  for (int t0 = 0; t0 < L_; t0 += 256) {
    int l = t0 + tid;
    float v = in[base + l * inner];
#pragma unroll
    for (int off = 1; off < 64; off <<= 1) {
      float n = __shfl_up(v, off, 64);
      if (lane >= off) v += n;
    }
    if (lane == 63) wsum[wid] = v;
    __syncthreads();
    float add = carry;
    for (int w = 0; w < wid; ++w) add += wsum[w];
    out[base + l * inner] = v + add;
    carry += wsum[0] + wsum[1] + wsum[2] + wsum[3];
    __syncthreads();
  }
}

// ---------------- scan_avg_bf: ctx = cumsum(x)/pos -> bf16 -----------------
__global__ void scan_avg_bf(const float* __restrict__ in, short* __restrict__ outb) {
  int row = blockIdx.x;
  int b = row / D_, r = row % D_;
  int base = b * L_ * D_ + r;
  int tid = threadIdx.x, lane = tid & 63, wid = tid >> 6;
  __shared__ float wsum[4];
  float carry = 0.f;
  for (int t0 = 0; t0 < L_; t0 += 256) {
    int l = t0 + tid;
    float v = in[base + l * D_];
#pragma unroll
    for (int off = 1; off < 64; off <<= 1) {
      float n = __shfl_up(v, off, 64);
      if (lane >= off) v += n;
    }
    if (lane == 63) wsum[wid] = v;
    __syncthreads();
    float add = carry;
    for (int w = 0; w < wid; ++w) add += wsum[w];
    outb[base + l * D_] = f2bf((v + add) / (float)(l + 1));
    carry += wsum[0] + wsum[1] + wsum[2] + wsum[3];
    __syncthreads();
  }
}

// ---------------- Kernel C3: storage phases from hs (sk2, VALU) ------------
__global__ void kernelC3(const short* __restrict__ hs_bf, const float* __restrict__ w_sk2,
                         const float* __restrict__ b_sk2,
                         float* __restrict__ spc, float* __restrict__ sps) {
  __shared__ float hsl[16][256];
  int tid = threadIdx.x;
  int tok0 = blockIdx.x * 16;
  for (int i = tid; i < 16 * 64; i += 256) {
    int t = i >> 6, c = i & 63;
    short4 v = *(const short4*)&hs_bf[(tok0 + t) * 256 + c * 4];
    hsl[t][c * 4 + 0] = bf2f(v.x);
    hsl[t][c * 4 + 1] = bf2f(v.y);
    hsl[t][c * 4 + 2] = bf2f(v.z);
    hsl[t][c * 4 + 3] = bf2f(v.w);
  }
  __syncthreads();
  for (int pass = 0; pass < 2; ++pass) {
    int t = pass * 8 + tid / 32, p = tid % 32;
    float a = b_sk2[p];
    for (int k = 0; k < 256; ++k) a += hsl[t][k] * w_sk2[k * 32 + p];
    float sp = tanhf(a) * PI_F;
    int idx = (tok0 + t) * 32 + p;
    spc[idx] = cosf(sp);
    sps[idx] = sinf(sp);
  }
}

// ---------------- Kernel D: per-chunk state sums ---------------------------
__global__ void kernelD(const float* __restrict__ spc, const float* __restrict__ sps,
                        const float* __restrict__ gv, float* __restrict__ U) {
  int bc = blockIdx.x;
  int b = bc / NC, c = bc % NC;
  int tid = threadIdx.x;
  __shared__ float sc[CL][P_];
  __shared__ float ss[CL][P_];
  int lbase = b * L_ + c * CL;
  for (int i = tid; i < CL * P_; i += 256) {
    sc[i / P_][i % P_] = spc[lbase * P_ + i];
    ss[i / P_][i % P_] = sps[lbase * P_ + i];
  }
  __syncthreads();
  float ac[P_], as2[P_];
#pragma unroll
  for (int p = 0; p < P_; ++p) { ac[p] = 0.f; as2[p] = 0.f; }
  for (int t = 0; t < CL; ++t) {
    float g = gv[(lbase + t) * D_ + tid];
#pragma unroll
    for (int p = 0; p < P_; ++p) {
      ac[p] += sc[t][p] * g;
      as2[p] += ss[t][p] * g;
    }
  }
  int ub = (bc * 2 * P_) * D_ + tid;
#pragma unroll
  for (int p = 0; p < P_; ++p) {
    U[ub + p * D_] = ac[p];
    U[ub + (P_ + p) * D_] = as2[p];
  }
}

// ---------------- Kernel E: in-place exclusive prefix over chunks ----------
__global__ void kernelE(float* __restrict__ U) {
  int tid = blockIdx.x * 256 + threadIdx.x;  // B*2*P*D = 65536
  int d = tid % D_;
  int p = (tid / D_) % P_;
  int path = (tid / (D_ * P_)) % 2;
  int b = tid / (D_ * P_ * 2);
  int base = ((b * NC) * 2 * P_ + path * P_ + p) * D_ + d;
  const int cs = 2 * P_ * D_;
  float run = 0.f;
  for (int c0 = 0; c0 < NC; c0 += 8) {
    float v[8];
#pragma unroll
    for (int j = 0; j < 8; ++j) v[j] = U[base + (c0 + j) * cs];
#pragma unroll
    for (int j = 0; j < 8; ++j) {
      U[base + (c0 + j) * cs] = run;
      run += v[j];
    }
  }
}

// ---------------- Kernel F: within-chunk scan + retrieval ------------------
__global__ void kernelF(const float* __restrict__ U, const float* __restrict__ spc,
                        const float* __restrict__ sps, const float* __restrict__ kcg,
                        const float* __restrict__ ksg, const float* __restrict__ gv,
                        const float* __restrict__ sgc, float* __restrict__ kvr) {
  int bc = blockIdx.x;
  int b = bc / NC, c = bc % NC;
  int tid = threadIdx.x;
  __shared__ __align__(16) float q[CL][P_][4];
  __shared__ float scl[CL];
  int lbase = b * L_ + c * CL;
  for (int i = tid; i < CL * P_; i += 256) {
    int t = i / P_, p = i % P_;
    int gi = lbase * P_ + i;
    q[t][p][0] = spc[gi];
    q[t][p][1] = sps[gi];
    q[t][p][2] = kcg[gi];
    q[t][p][3] = ksg[gi];
  }
  if (tid < CL) {
    float g = sgc[lbase + tid];
    scl[tid] = rsqrtf(fmaxf(g, 1.f)) * INV_SQRT_P;
  }
  float Sc[P_], Ss[P_];
  int ub = (bc * 2 * P_) * D_ + tid;
#pragma unroll
  for (int p = 0; p < P_; ++p) {
    Sc[p] = U[ub + p * D_];
    Ss[p] = U[ub + (P_ + p) * D_];
  }
  __syncthreads();
  for (int t = 0; t < CL; ++t) {
    float g = gv[(lbase + t) * D_ + tid];
    float retc = 0.f, rets = 0.f;
#pragma unroll
    for (int p = 0; p < P_; ++p) {
      float4 v = *(const float4*)&q[t][p][0];
      Sc[p] += v.x * g;
      retc += v.z * Sc[p];
      Ss[p] += v.y * g;
      rets += v.w * Ss[p];
    }
    kvr[(lbase + t) * D_ + tid] = (retc + rets) * scl[t];
  }
}

// ---------------- Kernel G1: pos_out + combine + LN -> bf16 ----------------
__global__ void kernelG1(const float* __restrict__ m1c, const float* __restrict__ m1s,
                         const float* __restrict__ qc, const float* __restrict__ qs,
                         const float* __restrict__ kvr,
                         const float* __restrict__ w_mem1o, const float* __restrict__ b_mem1o,
                         const float* __restrict__ ln_g, const float* __restrict__ ln_b,
                         short* __restrict__ cbn) {
  __shared__ float pr[TG][P_];
  __shared__ float cb[TG][D_];
  __shared__ float mu_s[TG], rs_s[TG];
  int tid = threadIdx.x;
  int tok0 = blockIdx.x * TG;
  for (int pass = 0; pass < 2; ++pass) {
    int t = pass * 8 + tid / 32, p = tid % 32;
    int idx = (tok0 + t) * P_ + p;
    pr[t][p] = (m1c[idx] * qc[idx] + m1s[idx] * qs[idx]) * INV_SQRT_P;
  }
  __syncthreads();
  int d = tid;
  {
    float accs[TG];
    float bm = b_mem1o[d];
#pragma unroll
    for (int t = 0; t < TG; ++t) accs[t] = bm;
    for (int p = 0; p < P_; ++p) {
      float w = w_mem1o[p * D_ + d];
#pragma unroll
      for (int t = 0; t < TG; ++t) accs[t] += pr[t][p] * w;
    }
#pragma unroll
    for (int t = 0; t < TG; ++t) cb[t][d] = accs[t] + kvr[(tok0 + t) * D_ + d];
  }
  __syncthreads();
  {
    int t = tid >> 4, kg = tid & 15;
    float s = 0.f, s2 = 0.f;
#pragma unroll
    for (int i = 0; i < 16; ++i) {
      float v = cb[t][kg + 16 * i];
      s += v;
      s2 += v * v;
    }
#pragma unroll
    for (int m = 1; m < 16; m <<= 1) {
      s += __shfl_xor(s, m, 64);
      s2 += __shfl_xor(s2, m, 64);
    }
    if (kg == 0) {
      float mu = s / (float)D_;
      float var = s2 / (float)D_ - mu * mu;
      mu_s[t] = mu;
      rs_s[t] = rsqrtf(var + 1e-5f);
    }
  }
  __syncthreads();
  {
    float lg = ln_g[d], lb = ln_b[d];
#pragma unroll
    for (int t = 0; t < TG; ++t)
      cbn[(tok0 + t) * D_ + d] = f2bf((cb[t][d] - mu_s[t]) * rs_s[t] * lg + lb);
  }
}

extern "C" void kernel_launch(void* const* d_in, const int* in_sizes, int n_in,
                              void* d_out, int out_size, void* d_ws, size_t ws_size,
                              hipStream_t stream) {
  const float* x = (const float*)d_in[0];
  const float* pos = (const float*)d_in[1];
  const float* w_mem1v = (const float*)d_in[2];
  const float* b_mem1v = (const float*)d_in[3];
  const float* w_mem1o = (const float*)d_in[4];
  const float* b_mem1o = (const float*)d_in[5];
  const float* w_off = (const float*)d_in[6];
  const float* b_off = (const float*)d_in[7];
  const float* w_key = (const float*)d_in[8];
  const float* b_key = (const float*)d_in[9];
  const float* w_val = (const float*)d_in[10];
  const float* b_val = (const float*)d_in[11];
  const float* w_sk1 = (const float*)d_in[12];
  const float* b_sk1 = (const float*)d_in[13];
  const float* w_sk2 = (const float*)d_in[14];
  const float* b_sk2 = (const float*)d_in[15];
  const float* w_gate = (const float*)d_in[16];
  const float* b_gate = (const float*)d_in[17];
  const float* ln_g = (const float*)d_in[18];
  const float* ln_b = (const float*)d_in[19];
  const float* w_out = (const float*)d_in[20];
  const float* b_out = (const float*)d_in[21];
  float* out = (float*)d_out;
  float* ws = (float*)d_ws;

  const int BLP = B_ * L_ * P_;  // 262144
  const int BLD = B_ * L_ * D_;  // 2097152
  // fp32 persistent arrays
  float* m1c = ws;
  float* m1s = m1c + BLP;
  float* qc = m1s + BLP;
  float* qs = qc + BLP;
  float* kc = qs + BLP;
  float* ks = kc + BLP;
  float* spc = ks + BLP;
  float* sps = spc + BLP;
  float* gv = sps + BLP;
  float* sg = gv + BLD;
  float* poff = sg + B_ * L_;
  // region B: Y [8192*384] fp32, later U [B*NC*2*P*D] fp32 (U larger)
  float* Y = poff + L_ * P_;
  float* U = Y;
  // region C: xbf|ctxbf|hs (bf16), later kvr fp32 over xbf+ctxbf(+hs head),
  // cbn bf16 after kvr (over hs tail + 0.4MB extra)
  float* regC = U + (size_t)B_ * NC * 2 * P_ * D_;
  short* xbf = (short*)regC;
  short* ctxbf = xbf + BLD;
  short* hs = ctxbf + BLD;
  float* kvr = regC;               // aliases xbf/ctxbf/hs-head (dead by then)
  short* cbn = (short*)(kvr + BLD);  // aliases hs tail (dead by then)
  short* WA = cbn + BLD;
  short* W1 = WA + 384 * 256;
  short* WO = W1 + 256 * 512;
  // total ~47 MB

  wprep<<<3456, 256, 0, stream>>>(x, pos, w_val, w_mem1v, w_off, b_off, w_key, w_gate,
                                  w_sk1, w_out, WA, W1, WO, xbf, poff);
  gemm_k<2, 6, 0><<<128 * 6, 256, 0, stream>>>(xbf, nullptr, WA, nullptr, nullptr, Y, nullptr);
  kernelA3<<<(B_ * L_) / 8, 256, 0, stream>>>(Y, pos, poff, b_mem1v, b_key, b_gate, b_val,
                                              m1c, m1s, qc, qs, kc, ks, gv, sg);
  scan2<<<2 * B_ * P_, 256, 0, stream>>>(m1c, m1s);
  scan_rows<<<B_, 256, 0, stream>>>(sg, sg, 1);
  scan_avg_bf<<<B_ * D_, 256, 0, stream>>>(x, ctxbf);
  gemm_k<4, 4, 1><<<128 * 4, 256, 0, stream>>>(xbf, ctxbf, W1, b_sk1, nullptr, nullptr, hs);
  kernelC3<<<(B_ * L_) / 16, 256, 0, stream>>>(hs, w_sk2, b_sk2, spc, sps);
  kernelD<<<B_ * NC, 256, 0, stream>>>(spc, sps, gv, U);
  kernelE<<<(B_ * 2 * P_ * D_) / 256, 256, 0, stream>>>(U);
  kernelF<<<B_ * NC, 256, 0, stream>>>(U, spc, sps, kc, ks, gv, sg, kvr);
  kernelG1<<<(B_ * L_) / TG, 256, 0, stream>>>(m1c, m1s, qc, qs, kvr, w_mem1o, b_mem1o,
                                               ln_g, ln_b, cbn);
  gemm_k<2, 4, 2><<<128 * 4, 256, 0, stream>>>(cbn, nullptr, WO, b_out, x, out, nullptr);
}

// Round 4
// 220.670 us; speedup vs baseline: 1.7858x; 1.1911x over previous
//
#include <hip/hip_runtime.h>
#include <hip/hip_bf16.h>

constexpr int B_ = 4;
constexpr int L_ = 2048;
constexpr int D_ = 256;
constexpr int P_ = 32;
constexpr int TG = 16;   // tokens/block kernel G1
constexpr int CL = 32;   // chunk length for KV scan
constexpr int NC = L_ / CL;  // 64 chunks

#define PI_F 3.14159265358979323846f
#define INV_SQRT_P 0.17677669529663687f  // 1/sqrt(32)

typedef __attribute__((ext_vector_type(8))) short short8_t;
typedef __attribute__((ext_vector_type(4))) float floatx4;

static __device__ inline short f2bf(float f) {
  unsigned int u;
  __builtin_memcpy(&u, &f, 4);
  unsigned int r = (u + 0x7fffu + ((u >> 16) & 1u)) >> 16;
  return (short)r;
}
static __device__ inline float bf2f(short s) {
  unsigned int u = ((unsigned int)(unsigned short)s) << 16;
  float f;
  __builtin_memcpy(&f, &u, 4);
  return f;
}

// ---------------- wprep: all weight casts/transposes + x->bf16 + poff ------
__global__ void wprep(const float* __restrict__ x, const float* __restrict__ pos,
                      const float* __restrict__ w_val, const float* __restrict__ w_mem1v,
                      const float* __restrict__ w_off, const float* __restrict__ b_off,
                      const float* __restrict__ w_key, const float* __restrict__ w_gate,
                      const float* __restrict__ w_sk1, const float* __restrict__ w_out,
                      short* __restrict__ WA, short* __restrict__ W1,
                      short* __restrict__ WO, short* __restrict__ xbf,
                      float* __restrict__ poff) {
  int blk = blockIdx.x, tid = threadIdx.x;
  if (blk < 384) {
    int idx = blk * 256 + tid;
    int n = idx >> 8, k = idx & 255;
    float v;
    if (n < 256) v = w_val[k * 256 + n];
    else if (n < 288) v = w_mem1v[k * 32 + (n - 256)];
    else if (n < 320) v = w_off[k * 32 + (n - 288)];
    else if (n < 352) v = w_key[k * 32 + (n - 320)];
    else if (n == 352) v = w_gate[k];
    else v = 0.f;
    WA[idx] = f2bf(v);
  } else if (blk < 896) {
    int idx = (blk - 384) * 256 + tid;
    int n = idx >> 9, k = idx & 511;
    W1[idx] = f2bf(w_sk1[k * 256 + n]);
  } else if (blk < 1152) {
    int idx = (blk - 896) * 256 + tid;
    int n = idx >> 8, k = idx & 255;
    WO[idx] = f2bf(w_out[k * 256 + n]);
  } else if (blk < 3200) {
    int idx = ((blk - 1152) * 256 + tid) * 4;
    float4 v = *(const float4*)&x[idx];
    short4 o;
    o.x = f2bf(v.x); o.y = f2bf(v.y); o.z = f2bf(v.z); o.w = f2bf(v.w);
    *(short4*)&xbf[idx] = o;
  } else {
    int idx = (blk - 3200) * 256 + tid;
    int l = idx >> 5, p = idx & 31;
    float a = b_off[p];
    for (int j = 0; j < 32; ++j) a += pos[l * 32 + j] * w_off[(256 + j) * 32 + p];
    poff[idx] = a;
  }
}

// ---------------- generic bf16 MFMA GEMM, 64x64 tile -----------------------
template <int KTILES, int NBLK, int MODE>
__global__ __launch_bounds__(256) void gemm_k(const short* __restrict__ A0,
                                              const short* __restrict__ A1,
                                              const short* __restrict__ W,
                                              const float* __restrict__ bias,
                                              const float* __restrict__ xres,
                                              float* __restrict__ outf,
                                              short* __restrict__ outb) {
  __shared__ short As[64][136];
  __shared__ short Bs[64][136];
  int tid = threadIdx.x;
  int mg = blockIdx.x / NBLK, ng = blockIdx.x % NBLK;
  int tok0 = mg * 64, n0 = ng * 64;
  int lane = tid & 63, w = tid >> 6;
  int mw = (w & 1) * 32, nw = (w >> 1) * 32;
  floatx4 acc[2][2] = {{{0.f, 0.f, 0.f, 0.f}, {0.f, 0.f, 0.f, 0.f}},
                       {{0.f, 0.f, 0.f, 0.f}, {0.f, 0.f, 0.f, 0.f}}};
  int r2 = tid >> 4, c8 = tid & 15;
  int ml = lane & 15, kq = (lane >> 4) * 8;
  const int K = KTILES * 128;

  for (int kt = 0; kt < KTILES; ++kt) {
    const short* Asrc;
    int cb;
    if (KTILES == 4) {
      Asrc = (kt < 2) ? A0 : A1;
      cb = (kt & 1) * 128;
    } else {
      Asrc = A0;
      cb = kt * 128;
    }
#pragma unroll
    for (int pass = 0; pass < 4; ++pass) {
      int row = pass * 16 + r2;
      *(short8_t*)&As[row][c8 * 8] =
          *(const short8_t*)&Asrc[(tok0 + row) * 256 + cb + c8 * 8];
      *(short8_t*)&Bs[row][c8 * 8] =
          *(const short8_t*)&W[(n0 + row) * K + kt * 128 + c8 * 8];
    }
    __syncthreads();
#pragma unroll
    for (int s = 0; s < 4; ++s) {
      short8_t a0 = *(short8_t*)&As[mw + ml][s * 32 + kq];
      short8_t a1 = *(short8_t*)&As[mw + 16 + ml][s * 32 + kq];
      short8_t b0 = *(short8_t*)&Bs[nw + ml][s * 32 + kq];
      short8_t b1 = *(short8_t*)&Bs[nw + 16 + ml][s * 32 + kq];
      acc[0][0] = __builtin_amdgcn_mfma_f32_16x16x32_bf16(a0, b0, acc[0][0], 0, 0, 0);
      acc[0][1] = __builtin_amdgcn_mfma_f32_16x16x32_bf16(a0, b1, acc[0][1], 0, 0, 0);
      acc[1][0] = __builtin_amdgcn_mfma_f32_16x16x32_bf16(a1, b0, acc[1][0], 0, 0, 0);
      acc[1][1] = __builtin_amdgcn_mfma_f32_16x16x32_bf16(a1, b1, acc[1][1], 0, 0, 0);
    }
    __syncthreads();
  }
  int col = lane & 15, rq = (lane >> 4) * 4;
#pragma unroll
  for (int nt = 0; nt < 2; ++nt) {
    int n = n0 + nw + nt * 16 + col;
    float bv = (MODE == 0) ? 0.f : bias[n];
#pragma unroll
    for (int mt = 0; mt < 2; ++mt) {
#pragma unroll
      for (int rg = 0; rg < 4; ++rg) {
        int tok = tok0 + mw + mt * 16 + rq + rg;
        float v = acc[mt][nt][rg] + bv;
        if (MODE == 0) {
          outf[tok * 384 + n] = v;
        } else if (MODE == 1) {
          float g = 0.5f * v * (1.f + erff(v * 0.70710678118654752f));
          outb[tok * 256 + n] = f2bf(g);
        } else {
          outf[tok * 256 + n] = xres[tok * 256 + n] + v;
        }
      }
    }
  }
}

// ---------------- Kernel A3: elementwise phasor prep from Y ----------------
__global__ void kernelA3(const float* __restrict__ Y, const float* __restrict__ pos,
                         const float* __restrict__ poff, const float* __restrict__ b_mem1v,
                         const float* __restrict__ b_key, const float* __restrict__ b_gate,
                         const float* __restrict__ b_val,
                         float* __restrict__ m1c, float* __restrict__ m1s,
                         float* __restrict__ qc, float* __restrict__ qs,
                         float* __restrict__ kc, float* __restrict__ ks,
                         float* __restrict__ gv, float* __restrict__ sg) {
  __shared__ float gsh[8];
  int tid = threadIdx.x;
  int tok0 = blockIdx.x * 8;
  int t = tid >> 5, p = tid & 31;
  int tok = tok0 + t, l = tok & (L_ - 1);
  float gate = 1.f / (1.f + expf(-(Y[tok * 384 + 352] + b_gate[0])));
  if (p == 0) {
    sg[tok] = gate;
    gsh[t] = gate;
  }
  float v1 = Y[tok * 384 + 256 + p] + b_mem1v[p];
  float ph = pos[l * 32 + p];
  float pc = cosf(ph), ps = sinf(ph);
  int idx = tok * 32 + p;
  m1c[idx] = pc * v1;
  m1s[idx] = ps * v1;
  float off = tanhf(Y[tok * 384 + 288 + p] + poff[l * 32 + p]) * PI_F;
  float oc = cosf(off), os = sinf(off);
  qc[idx] = pc * oc - ps * os;
  qs[idx] = ps * oc + pc * os;
  float kp = tanhf(Y[tok * 384 + 320 + p] + b_key[p]) * PI_F;
  kc[idx] = cosf(kp);
  ks[idx] = sinf(kp);
  __syncthreads();
  for (int tt = 0; tt < 8; ++tt) {
    gv[(tok0 + tt) * 256 + tid] = (Y[(tok0 + tt) * 384 + tid] + b_val[tid]) * gsh[tt];
  }
}

// ---------------- scan2: inclusive scan along L for m1c and m1s ------------
__global__ void scan2(float* __restrict__ a, float* __restrict__ b2) {
  float* arr = (blockIdx.x < B_ * P_) ? a : b2;
  int row = blockIdx.x & (B_ * P_ - 1);
  int b = row / P_, r = row % P_;
  int base = b * L_ * P_ + r;
  int tid = threadIdx.x, lane = tid & 63, wid = tid >> 6;
  __shared__ float wsum[4];
  float carry = 0.f;
  for (int t0 = 0; t0 < L_; t0 += 256) {
    int l = t0 + tid;
    float v = arr[base + l * P_];
#pragma unroll
    for (int off = 1; off < 64; off <<= 1) {
      float n = __shfl_up(v, off, 64);
      if (lane >= off) v += n;
    }
    if (lane == 63) wsum[wid] = v;
    __syncthreads();
    float add = carry;
    for (int w = 0; w < wid; ++w) add += wsum[w];
    arr[base + l * P_] = v + add;
    carry += wsum[0] + wsum[1] + wsum[2] + wsum[3];
    __syncthreads();
  }
}

// ---------------- scan_rows: generic fp32 inclusive scan -------------------
__global__ void scan_rows(const float* __restrict__ in, float* __restrict__ out,
                          int inner) {
  int row = blockIdx.x;
  int b = row / inner, r = row % inner;
  int base = b * L_ * inner + r;
  int tid = threadIdx.x, lane = tid & 63, wid = tid >> 6;
  __shared__ float wsum[4];
  float carry = 0.f;
  for (int t0 = 0; t0 < L_; t0 += 256) {
    int l = t0 + tid;
    float v = in[base + l * inner];
#pragma unroll
    for (int off = 1; off < 64; off <<= 1) {
      float n = __shfl_up(v, off, 64);
      if (lane >= off) v += n;
    }
    if (lane == 63) wsum[wid] = v;
    __syncthreads();
    float add = carry;
    for (int w = 0; w < wid; ++w) add += wsum[w];
    out[base + l * inner] = v + add;
    carry += wsum[0] + wsum[1] + wsum[2] + wsum[3];
    __syncthreads();
  }
}

// ---------------- scan_avg_bf: ctx = cumsum(x)/pos -> bf16 -----------------
__global__ void scan_avg_bf(const float* __restrict__ in, short* __restrict__ outb) {
  int row = blockIdx.x;
  int b = row / D_, r = row % D_;
  int base = b * L_ * D_ + r;
  int tid = threadIdx.x, lane = tid & 63, wid = tid >> 6;
  __shared__ float wsum[4];
  float carry = 0.f;
  for (int t0 = 0; t0 < L_; t0 += 256) {
    int l = t0 + tid;
    float v = in[base + l * D_];
#pragma unroll
    for (int off = 1; off < 64; off <<= 1) {
      float n = __shfl_up(v, off, 64);
      if (lane >= off) v += n;
    }
    if (lane == 63) wsum[wid] = v;
    __syncthreads();
    float add = carry;
    for (int w = 0; w < wid; ++w) add += wsum[w];
    outb[base + l * D_] = f2bf((v + add) / (float)(l + 1));
    carry += wsum[0] + wsum[1] + wsum[2] + wsum[3];
    __syncthreads();
  }
}

// ---------------- Kernel C3: storage phases from hs (sk2, VALU) ------------
__global__ void kernelC3(const short* __restrict__ hs_bf, const float* __restrict__ w_sk2,
                         const float* __restrict__ b_sk2,
                         float* __restrict__ spc, float* __restrict__ sps) {
  __shared__ float hsl[16][256];
  int tid = threadIdx.x;
  int tok0 = blockIdx.x * 16;
  for (int i = tid; i < 16 * 64; i += 256) {
    int t = i >> 6, c = i & 63;
    short4 v = *(const short4*)&hs_bf[(tok0 + t) * 256 + c * 4];
    hsl[t][c * 4 + 0] = bf2f(v.x);
    hsl[t][c * 4 + 1] = bf2f(v.y);
    hsl[t][c * 4 + 2] = bf2f(v.z);
    hsl[t][c * 4 + 3] = bf2f(v.w);
  }
  __syncthreads();
  for (int pass = 0; pass < 2; ++pass) {
    int t = pass * 8 + tid / 32, p = tid % 32;
    float a = b_sk2[p];
    for (int k = 0; k < 256; ++k) a += hsl[t][k] * w_sk2[k * 32 + p];
    float sp = tanhf(a) * PI_F;
    int idx = (tok0 + t) * 32 + p;
    spc[idx] = cosf(sp);
    sps[idx] = sinf(sp);
  }
}

// ---------------- Kernel D2: per-chunk state sums via MFMA -----------------
// U_chunk[64,256] = SP^T[64(q),32(t)] @ gv[32(t),256(d)], per (b,chunk)
__global__ __launch_bounds__(256) void kernelD2(const float* __restrict__ spc,
                                                const float* __restrict__ sps,
                                                const float* __restrict__ gv,
                                                float* __restrict__ U) {
  __shared__ __align__(16) short SPT[64][40];  // [q][t]
  __shared__ __align__(16) short Gt[256][40];  // [d][t]
  int tid = threadIdx.x;
  int bc = blockIdx.x;
  int lbase = bc * CL;
  // stage SPT (transpose spc/sps [t][p] -> [q][t])
  for (int it = 0; it < 4; ++it) {
    int idx = it * 256 + tid;  // t*32 + p
    int t = idx >> 5, p = idx & 31;
    int g = lbase * 32 + idx;
    SPT[p][t] = f2bf(spc[g]);
    SPT[32 + p][t] = f2bf(sps[g]);
  }
  // stage Gt (transpose gv [t][d] -> [d][t])
  for (int it = 0; it < 8; ++it) {
    int idx = it * 256 + tid;  // t*64 + d4
    int t = idx >> 6, d4 = idx & 63;
    float4 v = *(const float4*)&gv[(lbase + t) * 256 + d4 * 4];
    Gt[d4 * 4 + 0][t] = f2bf(v.x);
    Gt[d4 * 4 + 1][t] = f2bf(v.y);
    Gt[d4 * 4 + 2][t] = f2bf(v.z);
    Gt[d4 * 4 + 3][t] = f2bf(v.w);
  }
  __syncthreads();
  int lane = tid & 63, w = tid >> 6;
  int ml = lane & 15, quad = lane >> 4, kq = quad * 8;
  short8_t a[4], b[4];
#pragma unroll
  for (int mt = 0; mt < 4; ++mt) a[mt] = *(short8_t*)&SPT[mt * 16 + ml][kq];
#pragma unroll
  for (int nt = 0; nt < 4; ++nt) b[nt] = *(short8_t*)&Gt[w * 64 + nt * 16 + ml][kq];
  floatx4 acc[4][4] = {};
#pragma unroll
  for (int mt = 0; mt < 4; ++mt)
#pragma unroll
    for (int nt = 0; nt < 4; ++nt)
      acc[mt][nt] = __builtin_amdgcn_mfma_f32_16x16x32_bf16(a[mt], b[nt], acc[mt][nt], 0, 0, 0);
  int ub = bc * 64;
#pragma unroll
  for (int mt = 0; mt < 4; ++mt)
#pragma unroll
    for (int nt = 0; nt < 4; ++nt)
#pragma unroll
      for (int r = 0; r < 4; ++r) {
        int q = mt * 16 + quad * 4 + r;
        int d = w * 64 + nt * 16 + ml;
        U[(ub + q) * 256 + d] = acc[mt][nt][r];
      }
}

// ---------------- Kernel E: in-place exclusive prefix over chunks ----------
__global__ void kernelE(float* __restrict__ U) {
  int tid = blockIdx.x * 256 + threadIdx.x;  // B*2*P*D = 65536
  int d = tid % D_;
  int p = (tid / D_) % P_;
  int path = (tid / (D_ * P_)) % 2;
  int b = tid / (D_ * P_ * 2);
  int base = ((b * NC) * 2 * P_ + path * P_ + p) * D_ + d;
  const int cs = 2 * P_ * D_;
  float run = 0.f;
  for (int c0 = 0; c0 < NC; c0 += 8) {
    float v[8];
#pragma unroll
    for (int j = 0; j < 8; ++j) v[j] = U[base + (c0 + j) * cs];
#pragma unroll
    for (int j = 0; j < 8; ++j) {
      U[base + (c0 + j) * cs] = run;
      run += v[j];
    }
  }
}

// ---------------- Kernel F2: chunked linear-attention retrieval (MFMA) -----
// kvr[t,d] = scl[t] * ( K2[t,:] @ U_prev[:,d]  +  (masked S @ gv)[t,d] )
// S[t,s] = K2[t,:] @ SP[s,:]^T, masked s<=t.
__global__ __launch_bounds__(256) void kernelF2(const float* __restrict__ U,
                                                const float* __restrict__ spc,
                                                const float* __restrict__ sps,
                                                const float* __restrict__ kcg,
                                                const float* __restrict__ ksg,
                                                const float* __restrict__ gv,
                                                const float* __restrict__ sgc,
                                                float* __restrict__ kvr) {
  __shared__ __align__(16) short K2[32][72];   // [t][q]  q<32: cos-key, q>=32: sin-key
  __shared__ __align__(16) short SP[32][72];   // [s][q]; later overwritten by S[t][s]
  __shared__ __align__(16) short Ub[256][40];  // [d][q-half]
  __shared__ __align__(16) short Gt[256][40];  // [d][t]
  __shared__ float scl[32];
  int tid = threadIdx.x;
  int bc = blockIdx.x;
  int lbase = bc * CL;
  // stage K2, SP
  for (int it = 0; it < 4; ++it) {
    int idx = it * 256 + tid;
    int t = idx >> 5, p = idx & 31;
    int g = lbase * 32 + idx;
    K2[t][p] = f2bf(kcg[g]);
    K2[t][32 + p] = f2bf(ksg[g]);
    SP[t][p] = f2bf(spc[g]);
    SP[t][32 + p] = f2bf(sps[g]);
  }
  if (tid < 32) scl[tid] = rsqrtf(fmaxf(sgc[lbase + tid], 1.f)) * INV_SQRT_P;
  // stage Gt (gv transpose)
  for (int it = 0; it < 8; ++it) {
    int idx = it * 256 + tid;
    int t = idx >> 6, d4 = idx & 63;
    float4 v = *(const float4*)&gv[(lbase + t) * 256 + d4 * 4];
    Gt[d4 * 4 + 0][t] = f2bf(v.x);
    Gt[d4 * 4 + 1][t] = f2bf(v.y);
    Gt[d4 * 4 + 2][t] = f2bf(v.z);
    Gt[d4 * 4 + 3][t] = f2bf(v.w);
  }
  // stage Ub half 0 (q in [0,32))
  for (int it = 0; it < 8; ++it) {
    int idx = it * 256 + tid;
    int q = idx >> 6, d4 = idx & 63;
    float4 v = *(const float4*)&U[(bc * 64 + q) * 256 + d4 * 4];
    Ub[d4 * 4 + 0][q] = f2bf(v.x);
    Ub[d4 * 4 + 1][q] = f2bf(v.y);
    Ub[d4 * 4 + 2][q] = f2bf(v.z);
    Ub[d4 * 4 + 3][q] = f2bf(v.w);
  }
  __syncthreads();
  int lane = tid & 63, w = tid >> 6;
  int ml = lane & 15, quad = lane >> 4, kq = quad * 8;
  floatx4 acc[2][4] = {};
  // Part 1, ks=0: K2[:, 0:32] @ U_prev[0:32, :]
  {
    short8_t a0 = *(short8_t*)&K2[ml][kq];
    short8_t a1 = *(short8_t*)&K2[16 + ml][kq];
#pragma unroll
    for (int nt = 0; nt < 4; ++nt) {
      short8_t b = *(short8_t*)&Ub[w * 64 + nt * 16 + ml][kq];
      acc[0][nt] = __builtin_amdgcn_mfma_f32_16x16x32_bf16(a0, b, acc[0][nt], 0, 0, 0);
      acc[1][nt] = __builtin_amdgcn_mfma_f32_16x16x32_bf16(a1, b, acc[1][nt], 0, 0, 0);
    }
  }
  // wave 0: compute S = K2 @ SP^T, mask, write into SP buffer as S[t][s]
  if (w == 0) {
    floatx4 sacc[2][2] = {};
#pragma unroll
    for (int ks2 = 0; ks2 < 2; ++ks2) {
      short8_t a0 = *(short8_t*)&K2[ml][ks2 * 32 + kq];
      short8_t a1 = *(short8_t*)&K2[16 + ml][ks2 * 32 + kq];
      short8_t b0 = *(short8_t*)&SP[ml][ks2 * 32 + kq];
      short8_t b1 = *(short8_t*)&SP[16 + ml][ks2 * 32 + kq];
      sacc[0][0] = __builtin_amdgcn_mfma_f32_16x16x32_bf16(a0, b0, sacc[0][0], 0, 0, 0);
      sacc[0][1] = __builtin_amdgcn_mfma_f32_16x16x32_bf16(a0, b1, sacc[0][1], 0, 0, 0);
      sacc[1][0] = __builtin_amdgcn_mfma_f32_16x16x32_bf16(a1, b0, sacc[1][0], 0, 0, 0);
      sacc[1][1] = __builtin_amdgcn_mfma_f32_16x16x32_bf16(a1, b1, sacc[1][1], 0, 0, 0);
    }
#pragma unroll
    for (int mt = 0; mt < 2; ++mt)
#pragma unroll
      for (int nt = 0; nt < 2; ++nt)
#pragma unroll
        for (int r = 0; r < 4; ++r) {
          int trow = mt * 16 + quad * 4 + r;
          int scol = nt * 16 + ml;
          float v = (scol <= trow) ? sacc[mt][nt][r] : 0.f;
          SP[trow][scol] = f2bf(v);
        }
  }
  __syncthreads();
  // re-stage Ub half 1 (q in [32,64))
  for (int it = 0; it < 8; ++it) {
    int idx = it * 256 + tid;
    int q = idx >> 6, d4 = idx & 63;
    float4 v = *(const float4*)&U[(bc * 64 + 32 + q) * 256 + d4 * 4];
    Ub[d4 * 4 + 0][q] = f2bf(v.x);
    Ub[d4 * 4 + 1][q] = f2bf(v.y);
    Ub[d4 * 4 + 2][q] = f2bf(v.z);
    Ub[d4 * 4 + 3][q] = f2bf(v.w);
  }
  __syncthreads();
  // Part 1, ks=1: K2[:, 32:64] @ U_prev[32:64, :]
  {
    short8_t a0 = *(short8_t*)&K2[ml][32 + kq];
    short8_t a1 = *(short8_t*)&K2[16 + ml][32 + kq];
#pragma unroll
    for (int nt = 0; nt < 4; ++nt) {
      short8_t b = *(short8_t*)&Ub[w * 64 + nt * 16 + ml][kq];
      acc[0][nt] = __builtin_amdgcn_mfma_f32_16x16x32_bf16(a0, b, acc[0][nt], 0, 0, 0);
      acc[1][nt] = __builtin_amdgcn_mfma_f32_16x16x32_bf16(a1, b, acc[1][nt], 0, 0, 0);
    }
  }
  // Part 2: S @ gv  (S now lives in SP buffer, [t][s], K=32)
  {
    short8_t a0 = *(short8_t*)&SP[ml][kq];
    short8_t a1 = *(short8_t*)&SP[16 + ml][kq];
#pragma unroll
    for (int nt = 0; nt < 4; ++nt) {
      short8_t b = *(short8_t*)&Gt[w * 64 + nt * 16 + ml][kq];
      acc[0][nt] = __builtin_amdgcn_mfma_f32_16x16x32_bf16(a0, b, acc[0][nt], 0, 0, 0);
      acc[1][nt] = __builtin_amdgcn_mfma_f32_16x16x32_bf16(a1, b, acc[1][nt], 0, 0, 0);
    }
  }
  // epilogue: scale rows, store fp32
#pragma unroll
  for (int mt = 0; mt < 2; ++mt)
#pragma unroll
    for (int nt = 0; nt < 4; ++nt)
#pragma unroll
      for (int r = 0; r < 4; ++r) {
        int t = mt * 16 + quad * 4 + r;
        int d = w * 64 + nt * 16 + ml;
        kvr[(lbase + t) * 256 + d] = acc[mt][nt][r] * scl[t];
      }
}

// ---------------- Kernel G1: pos_out + combine + LN -> bf16 ----------------
__global__ void kernelG1(const float* __restrict__ m1c, const float* __restrict__ m1s,
                         const float* __restrict__ qc, const float* __restrict__ qs,
                         const float* __restrict__ kvr,
                         const float* __restrict__ w_mem1o, const float* __restrict__ b_mem1o,
                         const float* __restrict__ ln_g, const float* __restrict__ ln_b,
                         short* __restrict__ cbn) {
  __shared__ float pr[TG][P_];
  __shared__ float cb[TG][D_];
  __shared__ float mu_s[TG], rs_s[TG];
  int tid = threadIdx.x;
  int tok0 = blockIdx.x * TG;
  for (int pass = 0; pass < 2; ++pass) {
    int t = pass * 8 + tid / 32, p = tid % 32;
    int idx = (tok0 + t) * P_ + p;
    pr[t][p] = (m1c[idx] * qc[idx] + m1s[idx] * qs[idx]) * INV_SQRT_P;
  }
  __syncthreads();
  int d = tid;
  {
    float accs[TG];
    float bm = b_mem1o[d];
#pragma unroll
    for (int t = 0; t < TG; ++t) accs[t] = bm;
    for (int p = 0; p < P_; ++p) {
      float w = w_mem1o[p * D_ + d];
#pragma unroll
      for (int t = 0; t < TG; ++t) accs[t] += pr[t][p] * w;
    }
#pragma unroll
    for (int t = 0; t < TG; ++t) cb[t][d] = accs[t] + kvr[(tok0 + t) * D_ + d];
  }
  __syncthreads();
  {
    int t = tid >> 4, kg = tid & 15;
    float s = 0.f, s2 = 0.f;
#pragma unroll
    for (int i = 0; i < 16; ++i) {
      float v = cb[t][kg + 16 * i];
      s += v;
      s2 += v * v;
    }
#pragma unroll
    for (int m = 1; m < 16; m <<= 1) {
      s += __shfl_xor(s, m, 64);
      s2 += __shfl_xor(s2, m, 64);
    }
    if (kg == 0) {
      float mu = s / (float)D_;
      float var = s2 / (float)D_ - mu * mu;
      mu_s[t] = mu;
      rs_s[t] = rsqrtf(var + 1e-5f);
    }
  }
  __syncthreads();
  {
    float lg = ln_g[d], lb = ln_b[d];
#pragma unroll
    for (int t = 0; t < TG; ++t)
      cbn[(tok0 + t) * D_ + d] = f2bf((cb[t][d] - mu_s[t]) * rs_s[t] * lg + lb);
  }
}

extern "C" void kernel_launch(void* const* d_in, const int* in_sizes, int n_in,
                              void* d_out, int out_size, void* d_ws, size_t ws_size,
                              hipStream_t stream) {
  const float* x = (const float*)d_in[0];
  const float* pos = (const float*)d_in[1];
  const float* w_mem1v = (const float*)d_in[2];
  const float* b_mem1v = (const float*)d_in[3];
  const float* w_mem1o = (const float*)d_in[4];
  const float* b_mem1o = (const float*)d_in[5];
  const float* w_off = (const float*)d_in[6];
  const float* b_off = (const float*)d_in[7];
  const float* w_key = (const float*)d_in[8];
  const float* b_key = (const float*)d_in[9];
  const float* w_val = (const float*)d_in[10];
  const float* b_val = (const float*)d_in[11];
  const float* w_sk1 = (const float*)d_in[12];
  const float* b_sk1 = (const float*)d_in[13];
  const float* w_sk2 = (const float*)d_in[14];
  const float* b_sk2 = (const float*)d_in[15];
  const float* w_gate = (const float*)d_in[16];
  const float* b_gate = (const float*)d_in[17];
  const float* ln_g = (const float*)d_in[18];
  const float* ln_b = (const float*)d_in[19];
  const float* w_out = (const float*)d_in[20];
  const float* b_out = (const float*)d_in[21];
  float* out = (float*)d_out;
  float* ws = (float*)d_ws;

  const int BLP = B_ * L_ * P_;  // 262144
  const int BLD = B_ * L_ * D_;  // 2097152
  float* m1c = ws;
  float* m1s = m1c + BLP;
  float* qc = m1s + BLP;
  float* qs = qc + BLP;
  float* kc = qs + BLP;
  float* ks = kc + BLP;
  float* spc = ks + BLP;
  float* sps = spc + BLP;
  float* gv = sps + BLP;
  float* sg = gv + BLD;
  float* poff = sg + B_ * L_;
  float* Y = poff + L_ * P_;
  float* U = Y;
  float* regC = U + (size_t)B_ * NC * 2 * P_ * D_;
  short* xbf = (short*)regC;
  short* ctxbf = xbf + BLD;
  short* hs = ctxbf + BLD;
  float* kvr = regC;
  short* cbn = (short*)(kvr + BLD);
  short* WA = cbn + BLD;
  short* W1 = WA + 384 * 256;
  short* WO = W1 + 256 * 512;

  wprep<<<3456, 256, 0, stream>>>(x, pos, w_val, w_mem1v, w_off, b_off, w_key, w_gate,
                                  w_sk1, w_out, WA, W1, WO, xbf, poff);
  gemm_k<2, 6, 0><<<128 * 6, 256, 0, stream>>>(xbf, nullptr, WA, nullptr, nullptr, Y, nullptr);
  kernelA3<<<(B_ * L_) / 8, 256, 0, stream>>>(Y, pos, poff, b_mem1v, b_key, b_gate, b_val,
                                              m1c, m1s, qc, qs, kc, ks, gv, sg);
  scan2<<<2 * B_ * P_, 256, 0, stream>>>(m1c, m1s);
  scan_rows<<<B_, 256, 0, stream>>>(sg, sg, 1);
  scan_avg_bf<<<B_ * D_, 256, 0, stream>>>(x, ctxbf);
  gemm_k<4, 4, 1><<<128 * 4, 256, 0, stream>>>(xbf, ctxbf, W1, b_sk1, nullptr, nullptr, hs);
  kernelC3<<<(B_ * L_) / 16, 256, 0, stream>>>(hs, w_sk2, b_sk2, spc, sps);
  kernelD2<<<B_ * NC, 256, 0, stream>>>(spc, sps, gv, U);
  kernelE<<<(B_ * 2 * P_ * D_) / 256, 256, 0, stream>>>(U);
  kernelF2<<<B_ * NC, 256, 0, stream>>>(U, spc, sps, kc, ks, gv, sg, kvr);
  kernelG1<<<(B_ * L_) / TG, 256, 0, stream>>>(m1c, m1s, qc, qs, kvr, w_mem1o, b_mem1o,
                                               ln_g, ln_b, cbn);
  gemm_k<2, 4, 2><<<128 * 4, 256, 0, stream>>>(cbn, nullptr, WO, b_out, x, out, nullptr);
}

// Round 5
// 202.467 us; speedup vs baseline: 1.9464x; 1.0899x over previous
//
#include <hip/hip_runtime.h>
#include <hip/hip_bf16.h>

constexpr int B_ = 4;
constexpr int L_ = 2048;
constexpr int D_ = 256;
constexpr int P_ = 32;
constexpr int TG = 16;   // tokens/block kernel G1
constexpr int CL = 32;   // chunk length for KV scan
constexpr int NC = L_ / CL;  // 64 chunks

#define PI_F 3.14159265358979323846f
#define INV_SQRT_P 0.17677669529663687f  // 1/sqrt(32)

typedef __attribute__((ext_vector_type(8))) short short8_t;
typedef __attribute__((ext_vector_type(4))) float floatx4;

static __device__ inline short f2bf(float f) {
  unsigned int u;
  __builtin_memcpy(&u, &f, 4);
  unsigned int r = (u + 0x7fffu + ((u >> 16) & 1u)) >> 16;
  return (short)r;
}
static __device__ inline float bf2f(short s) {
  unsigned int u = ((unsigned int)(unsigned short)s) << 16;
  float f;
  __builtin_memcpy(&f, &u, 4);
  return f;
}

// ---------------- wprep: weight casts/transposes + x->bf16 + poff ----------
__global__ void wprep(const float* __restrict__ x, const float* __restrict__ pos,
                      const float* __restrict__ w_val, const float* __restrict__ w_mem1v,
                      const float* __restrict__ w_off, const float* __restrict__ b_off,
                      const float* __restrict__ w_key, const float* __restrict__ w_gate,
                      const float* __restrict__ w_sk1, const float* __restrict__ w_out,
                      const float* __restrict__ w_sk2,
                      short* __restrict__ WA, short* __restrict__ W1,
                      short* __restrict__ WO, short* __restrict__ W2T,
                      short* __restrict__ xbf, float* __restrict__ poff) {
  int blk = blockIdx.x, tid = threadIdx.x;
  if (blk < 384) {
    int idx = blk * 256 + tid;
    int n = idx >> 8, k = idx & 255;
    float v;
    if (n < 256) v = w_val[k * 256 + n];
    else if (n < 288) v = w_mem1v[k * 32 + (n - 256)];
    else if (n < 320) v = w_off[k * 32 + (n - 288)];
    else if (n < 352) v = w_key[k * 32 + (n - 320)];
    else if (n == 352) v = w_gate[k];
    else v = 0.f;
    WA[idx] = f2bf(v);
  } else if (blk < 896) {
    int idx = (blk - 384) * 256 + tid;
    int n = idx >> 9, k = idx & 511;
    W1[idx] = f2bf(w_sk1[k * 256 + n]);
  } else if (blk < 1152) {
    int idx = (blk - 896) * 256 + tid;
    int n = idx >> 8, k = idx & 255;
    WO[idx] = f2bf(w_out[k * 256 + n]);
  } else if (blk < 1184) {
    int idx = (blk - 1152) * 256 + tid;  // p*256 + k
    int p = idx >> 8, k = idx & 255;
    W2T[idx] = f2bf(w_sk2[k * 32 + p]);
  } else if (blk < 3232) {
    int idx = ((blk - 1184) * 256 + tid) * 4;
    float4 v = *(const float4*)&x[idx];
    short4 o;
    o.x = f2bf(v.x); o.y = f2bf(v.y); o.z = f2bf(v.z); o.w = f2bf(v.w);
    *(short4*)&xbf[idx] = o;
  } else {
    int idx = (blk - 3232) * 256 + tid;
    int l = idx >> 5, p = idx & 31;
    float a = b_off[p];
    for (int j = 0; j < 32; ++j) a += pos[l * 32 + j] * w_off[(256 + j) * 32 + p];
    poff[idx] = a;
  }
}

// ---------------- generic bf16 MFMA GEMM, 64x64 tile -----------------------
template <int KTILES, int NBLK, int MODE>
__global__ __launch_bounds__(256) void gemm_k(const short* __restrict__ A0,
                                              const short* __restrict__ A1,
                                              const short* __restrict__ W,
                                              const float* __restrict__ bias,
                                              const float* __restrict__ xres,
                                              float* __restrict__ outf,
                                              short* __restrict__ outb) {
  __shared__ short As[64][136];
  __shared__ short Bs[64][136];
  int tid = threadIdx.x;
  int mg = blockIdx.x / NBLK, ng = blockIdx.x % NBLK;
  int tok0 = mg * 64, n0 = ng * 64;
  int lane = tid & 63, w = tid >> 6;
  int mw = (w & 1) * 32, nw = (w >> 1) * 32;
  floatx4 acc[2][2] = {{{0.f, 0.f, 0.f, 0.f}, {0.f, 0.f, 0.f, 0.f}},
                       {{0.f, 0.f, 0.f, 0.f}, {0.f, 0.f, 0.f, 0.f}}};
  int r2 = tid >> 4, c8 = tid & 15;
  int ml = lane & 15, kq = (lane >> 4) * 8;
  const int K = KTILES * 128;

  for (int kt = 0; kt < KTILES; ++kt) {
    const short* Asrc;
    int cb;
    if (KTILES == 4) {
      Asrc = (kt < 2) ? A0 : A1;
      cb = (kt & 1) * 128;
    } else {
      Asrc = A0;
      cb = kt * 128;
    }
#pragma unroll
    for (int pass = 0; pass < 4; ++pass) {
      int row = pass * 16 + r2;
      *(short8_t*)&As[row][c8 * 8] =
          *(const short8_t*)&Asrc[(tok0 + row) * 256 + cb + c8 * 8];
      *(short8_t*)&Bs[row][c8 * 8] =
          *(const short8_t*)&W[(n0 + row) * K + kt * 128 + c8 * 8];
    }
    __syncthreads();
#pragma unroll
    for (int s = 0; s < 4; ++s) {
      short8_t a0 = *(short8_t*)&As[mw + ml][s * 32 + kq];
      short8_t a1 = *(short8_t*)&As[mw + 16 + ml][s * 32 + kq];
      short8_t b0 = *(short8_t*)&Bs[nw + ml][s * 32 + kq];
      short8_t b1 = *(short8_t*)&Bs[nw + 16 + ml][s * 32 + kq];
      acc[0][0] = __builtin_amdgcn_mfma_f32_16x16x32_bf16(a0, b0, acc[0][0], 0, 0, 0);
      acc[0][1] = __builtin_amdgcn_mfma_f32_16x16x32_bf16(a0, b1, acc[0][1], 0, 0, 0);
      acc[1][0] = __builtin_amdgcn_mfma_f32_16x16x32_bf16(a1, b0, acc[1][0], 0, 0, 0);
      acc[1][1] = __builtin_amdgcn_mfma_f32_16x16x32_bf16(a1, b1, acc[1][1], 0, 0, 0);
    }
    __syncthreads();
  }
  int col = lane & 15, rq = (lane >> 4) * 4;
#pragma unroll
  for (int nt = 0; nt < 2; ++nt) {
    int n = n0 + nw + nt * 16 + col;
    float bv = (MODE == 0) ? 0.f : bias[n];
#pragma unroll
    for (int mt = 0; mt < 2; ++mt) {
#pragma unroll
      for (int rg = 0; rg < 4; ++rg) {
        int tok = tok0 + mw + mt * 16 + rq + rg;
        float v = acc[mt][nt][rg] + bv;
        if (MODE == 0) {
          outf[tok * 384 + n] = v;
        } else if (MODE == 1) {
          float g = 0.5f * v * (1.f + erff(v * 0.70710678118654752f));
          outb[tok * 256 + n] = f2bf(g);
        } else {
          outf[tok * 256 + n] = xres[tok * 256 + n] + v;
        }
      }
    }
  }
}

// ---------------- Kernel A3: elementwise phasor prep from Y ----------------
// writes m1c/m1s/qc/qs (fp32), sg, K2bf [tok][64] bf16, gvT [b][c][d][32] bf16
__global__ void kernelA3(const float* __restrict__ Y, const float* __restrict__ pos,
                         const float* __restrict__ poff, const float* __restrict__ b_mem1v,
                         const float* __restrict__ b_key, const float* __restrict__ b_gate,
                         const float* __restrict__ b_val,
                         float* __restrict__ m1c, float* __restrict__ m1s,
                         float* __restrict__ qc, float* __restrict__ qs,
                         short* __restrict__ K2bf, short* __restrict__ gvT,
                         float* __restrict__ sg) {
  __shared__ float gsh[8];
  int tid = threadIdx.x;
  int tok0 = blockIdx.x * 8;
  int t = tid >> 5, p = tid & 31;
  int tok = tok0 + t, l = tok & (L_ - 1);
  float gate = 1.f / (1.f + expf(-(Y[tok * 384 + 352] + b_gate[0])));
  if (p == 0) {
    sg[tok] = gate;
    gsh[t] = gate;
  }
  float v1 = Y[tok * 384 + 256 + p] + b_mem1v[p];
  float ph = pos[l * 32 + p];
  float pc = cosf(ph), ps = sinf(ph);
  int idx = tok * 32 + p;
  m1c[idx] = pc * v1;
  m1s[idx] = ps * v1;
  float off = tanhf(Y[tok * 384 + 288 + p] + poff[l * 32 + p]) * PI_F;
  float oc = cosf(off), os = sinf(off);
  qc[idx] = pc * oc - ps * os;
  qs[idx] = ps * oc + pc * os;
  float kp = tanhf(Y[tok * 384 + 320 + p] + b_key[p]) * PI_F;
  K2bf[tok * 64 + p] = f2bf(cosf(kp));
  K2bf[tok * 64 + 32 + p] = f2bf(sinf(kp));
  __syncthreads();
  // gv, transposed-bf16 per chunk: gvT[(bc*256 + d)*32 + tloc]
  {
    int b = tok0 / L_;
    int l0 = tok0 & (L_ - 1);
    int bc = b * NC + (l0 >> 5);
    int tl0 = l0 & 31;
    short sv[8];
#pragma unroll
    for (int tt = 0; tt < 8; ++tt)
      sv[tt] = f2bf((Y[(tok0 + tt) * 384 + tid] + b_val[tid]) * gsh[tt]);
    *(short8_t*)&gvT[(bc * 256 + tid) * 32 + tl0] = *(short8_t*)sv;
  }
}

// ---------------- scan_all: fused scans --------------------------------------
// blk < 256: m1c/m1s rows (inner=P). blk in [256,260): sg (inner=1).
// blk >= 260: ctx rows (inner=D), avg + bf16 out.
__global__ void scan_all(float* __restrict__ m1c, float* __restrict__ m1s,
                         float* __restrict__ sg, const float* __restrict__ x,
                         short* __restrict__ ctxbf) {
  int blk = blockIdx.x;
  int tid = threadIdx.x, lane = tid & 63, wid = tid >> 6;
  __shared__ float wsum[4];
  float carry = 0.f;
  float* arr = nullptr;
  const float* src = nullptr;
  int base, inner, mode;
  if (blk < 256) {
    arr = (blk < 128) ? m1c : m1s;
    int row = blk & 127;
    int b = row >> 5, r = row & 31;
    base = b * L_ * P_ + r;
    inner = P_;
    mode = 0;
    src = arr;
  } else if (blk < 260) {
    arr = sg;
    base = (blk - 256) * L_;
    inner = 1;
    mode = 0;
    src = arr;
  } else {
    int row = blk - 260;
    int b = row >> 8, r = row & 255;
    base = b * L_ * D_ + r;
    inner = D_;
    mode = 1;
    src = x;
  }
  for (int t0 = 0; t0 < L_; t0 += 256) {
    int l = t0 + tid;
    float v = src[base + l * inner];
#pragma unroll
    for (int off = 1; off < 64; off <<= 1) {
      float n = __shfl_up(v, off, 64);
      if (lane >= off) v += n;
    }
    if (lane == 63) wsum[wid] = v;
    __syncthreads();
    float add = carry;
    for (int w = 0; w < wid; ++w) add += wsum[w];
    float res = v + add;
    if (mode == 0) arr[base + l * inner] = res;
    else ctxbf[base + l * inner] = f2bf(res / (float)(l + 1));
    carry += wsum[0] + wsum[1] + wsum[2] + wsum[3];
    __syncthreads();
  }
}

// ---------------- Kernel C3m: storage phases via MFMA ----------------------
// sp = tanh(hs @ w_sk2 + b_sk2)*PI; writes spT [b][c][q][t] and SPbf [t][64]
__global__ __launch_bounds__(256) void kernelC3m(const short* __restrict__ hs,
                                                 const short* __restrict__ W2T,
                                                 const float* __restrict__ b_sk2,
                                                 short* __restrict__ spT,
                                                 short* __restrict__ SPbf) {
  int tid = threadIdx.x;
  int tok0 = blockIdx.x * 64;
  int lane = tid & 63, w = tid >> 6;
  int ml = lane & 15, quad = lane >> 4, kq = quad * 8;
  int m0 = w * 16;
  floatx4 acc[2] = {};
#pragma unroll
  for (int s = 0; s < 8; ++s) {
    short8_t a = *(const short8_t*)&hs[(tok0 + m0 + ml) * 256 + s * 32 + kq];
    short8_t b0 = *(const short8_t*)&W2T[ml * 256 + s * 32 + kq];
    short8_t b1 = *(const short8_t*)&W2T[(16 + ml) * 256 + s * 32 + kq];
    acc[0] = __builtin_amdgcn_mfma_f32_16x16x32_bf16(a, b0, acc[0], 0, 0, 0);
    acc[1] = __builtin_amdgcn_mfma_f32_16x16x32_bf16(a, b1, acc[1], 0, 0, 0);
  }
#pragma unroll
  for (int nt = 0; nt < 2; ++nt) {
    int p = nt * 16 + ml;
    float bs = b_sk2[p];
#pragma unroll
    for (int r = 0; r < 4; ++r) {
      int tok = tok0 + m0 + quad * 4 + r;
      float sp = tanhf(acc[nt][r] + bs) * PI_F;
      short c = f2bf(cosf(sp)), s = f2bf(sinf(sp));
      int b = tok / L_, l = tok & (L_ - 1);
      int bc = b * NC + (l >> 5), tl = l & 31;
      spT[(bc * 64 + p) * 32 + tl] = c;
      spT[(bc * 64 + 32 + p) * 32 + tl] = s;
      SPbf[tok * 64 + p] = c;
      SPbf[tok * 64 + 32 + p] = s;
    }
  }
}

// ---------------- Kernel D2: per-chunk state sums, LDS-free MFMA -----------
// U_chunk[64,256] = spT[q][t] @ gvT[d][t]^T per (b,chunk)
__global__ __launch_bounds__(256) void kernelD2(const short* __restrict__ spT,
                                                const short* __restrict__ gvT,
                                                float* __restrict__ U) {
  int tid = threadIdx.x;
  int bc = blockIdx.x;
  int lane = tid & 63, w = tid >> 6;
  int ml = lane & 15, quad = lane >> 4, kq = quad * 8;
  short8_t a[4], b[4];
#pragma unroll
  for (int mt = 0; mt < 4; ++mt)
    a[mt] = *(const short8_t*)&spT[(bc * 64 + mt * 16 + ml) * 32 + kq];
#pragma unroll
  for (int nt = 0; nt < 4; ++nt)
    b[nt] = *(const short8_t*)&gvT[(bc * 256 + w * 64 + nt * 16 + ml) * 32 + kq];
  floatx4 acc[4][4] = {};
#pragma unroll
  for (int mt = 0; mt < 4; ++mt)
#pragma unroll
    for (int nt = 0; nt < 4; ++nt)
      acc[mt][nt] = __builtin_amdgcn_mfma_f32_16x16x32_bf16(a[mt], b[nt], acc[mt][nt], 0, 0, 0);
  int ub = bc * 64;
#pragma unroll
  for (int mt = 0; mt < 4; ++mt)
#pragma unroll
    for (int nt = 0; nt < 4; ++nt)
#pragma unroll
      for (int r = 0; r < 4; ++r) {
        int q = mt * 16 + quad * 4 + r;
        int d = w * 64 + nt * 16 + ml;
        U[(ub + q) * 256 + d] = acc[mt][nt][r];
      }
}

// ---------------- Kernel E: in-place exclusive prefix over chunks ----------
__global__ void kernelE(float* __restrict__ U) {
  int tid = blockIdx.x * 256 + threadIdx.x;  // B*64*D = 65536
  int d = tid % D_;
  int q = (tid / D_) % 64;
  int b = tid / (D_ * 64);
  int base = ((b * NC) * 64 + q) * D_ + d;
  const int cs = 64 * D_;
  float run = 0.f;
  for (int c0 = 0; c0 < NC; c0 += 8) {
    float v[8];
#pragma unroll
    for (int j = 0; j < 8; ++j) v[j] = U[base + (c0 + j) * cs];
#pragma unroll
    for (int j = 0; j < 8; ++j) {
      U[base + (c0 + j) * cs] = run;
      run += v[j];
    }
  }
}

// ---------------- Kernel F2: chunked linear-attention retrieval (MFMA) -----
__global__ __launch_bounds__(256) void kernelF2(const float* __restrict__ U,
                                                const short* __restrict__ SPbf,
                                                const short* __restrict__ K2bf,
                                                const short* __restrict__ gvT,
                                                const float* __restrict__ sgc,
                                                float* __restrict__ kvr) {
  __shared__ __align__(16) short Ub[256][40];  // [d][q-half]
  __shared__ __align__(16) short SL[32][40];   // masked S [t][s]
  __shared__ float scl[32];
  int tid = threadIdx.x;
  int bc = blockIdx.x;
  int lbase = bc * CL;
  if (tid < 32) scl[tid] = rsqrtf(fmaxf(sgc[lbase + tid], 1.f)) * INV_SQRT_P;
  // stage Ub half 0 (q in [0,32))
  for (int it = 0; it < 8; ++it) {
    int idx = it * 256 + tid;
    int q = idx >> 6, d4 = idx & 63;
    float4 v = *(const float4*)&U[(bc * 64 + q) * 256 + d4 * 4];
    Ub[d4 * 4 + 0][q] = f2bf(v.x);
    Ub[d4 * 4 + 1][q] = f2bf(v.y);
    Ub[d4 * 4 + 2][q] = f2bf(v.z);
    Ub[d4 * 4 + 3][q] = f2bf(v.w);
  }
  __syncthreads();
  int lane = tid & 63, w = tid >> 6;
  int ml = lane & 15, quad = lane >> 4, kq = quad * 8;
  floatx4 acc[2][4] = {};
  short8_t ka0 = *(const short8_t*)&K2bf[(lbase + ml) * 64 + kq];
  short8_t ka1 = *(const short8_t*)&K2bf[(lbase + 16 + ml) * 64 + kq];
  short8_t kb0 = *(const short8_t*)&K2bf[(lbase + ml) * 64 + 32 + kq];
  short8_t kb1 = *(const short8_t*)&K2bf[(lbase + 16 + ml) * 64 + 32 + kq];
  // Part 1, ks=0: K2[:, 0:32] @ U_prev[0:32, :]
#pragma unroll
  for (int nt = 0; nt < 4; ++nt) {
    short8_t b = *(short8_t*)&Ub[w * 64 + nt * 16 + ml][kq];
    acc[0][nt] = __builtin_amdgcn_mfma_f32_16x16x32_bf16(ka0, b, acc[0][nt], 0, 0, 0);
    acc[1][nt] = __builtin_amdgcn_mfma_f32_16x16x32_bf16(ka1, b, acc[1][nt], 0, 0, 0);
  }
  // wave 0: S = K2 @ SP^T, mask, write SL[t][s]
  if (w == 0) {
    floatx4 sacc[2][2] = {};
#pragma unroll
    for (int ks2 = 0; ks2 < 2; ++ks2) {
      short8_t a0 = (ks2 == 0) ? ka0 : kb0;
      short8_t a1 = (ks2 == 0) ? ka1 : kb1;
      short8_t b0 = *(const short8_t*)&SPbf[(lbase + ml) * 64 + ks2 * 32 + kq];
      short8_t b1 = *(const short8_t*)&SPbf[(lbase + 16 + ml) * 64 + ks2 * 32 + kq];
      sacc[0][0] = __builtin_amdgcn_mfma_f32_16x16x32_bf16(a0, b0, sacc[0][0], 0, 0, 0);
      sacc[0][1] = __builtin_amdgcn_mfma_f32_16x16x32_bf16(a0, b1, sacc[0][1], 0, 0, 0);
      sacc[1][0] = __builtin_amdgcn_mfma_f32_16x16x32_bf16(a1, b0, sacc[1][0], 0, 0, 0);
      sacc[1][1] = __builtin_amdgcn_mfma_f32_16x16x32_bf16(a1, b1, sacc[1][1], 0, 0, 0);
    }
#pragma unroll
    for (int mt = 0; mt < 2; ++mt)
#pragma unroll
      for (int nt = 0; nt < 2; ++nt)
#pragma unroll
        for (int r = 0; r < 4; ++r) {
          int trow = mt * 16 + quad * 4 + r;
          int scol = nt * 16 + ml;
          float v = (scol <= trow) ? sacc[mt][nt][r] : 0.f;
          SL[trow][scol] = f2bf(v);
        }
  }
  __syncthreads();
  // re-stage Ub half 1 (q in [32,64))
  for (int it = 0; it < 8; ++it) {
    int idx = it * 256 + tid;
    int q = idx >> 6, d4 = idx & 63;
    float4 v = *(const float4*)&U[(bc * 64 + 32 + q) * 256 + d4 * 4];
    Ub[d4 * 4 + 0][q] = f2bf(v.x);
    Ub[d4 * 4 + 1][q] = f2bf(v.y);
    Ub[d4 * 4 + 2][q] = f2bf(v.z);
    Ub[d4 * 4 + 3][q] = f2bf(v.w);
  }
  __syncthreads();
  // Part 1, ks=1: K2[:, 32:64] @ U_prev[32:64, :]
#pragma unroll
  for (int nt = 0; nt < 4; ++nt) {
    short8_t b = *(short8_t*)&Ub[w * 64 + nt * 16 + ml][kq];
    acc[0][nt] = __builtin_amdgcn_mfma_f32_16x16x32_bf16(kb0, b, acc[0][nt], 0, 0, 0);
    acc[1][nt] = __builtin_amdgcn_mfma_f32_16x16x32_bf16(kb1, b, acc[1][nt], 0, 0, 0);
  }
  // Part 2: S @ gv (A from SL, B direct from gvT)
  {
    short8_t a0 = *(short8_t*)&SL[ml][kq];
    short8_t a1 = *(short8_t*)&SL[16 + ml][kq];
#pragma unroll
    for (int nt = 0; nt < 4; ++nt) {
      short8_t b = *(const short8_t*)&gvT[(bc * 256 + w * 64 + nt * 16 + ml) * 32 + kq];
      acc[0][nt] = __builtin_amdgcn_mfma_f32_16x16x32_bf16(a0, b, acc[0][nt], 0, 0, 0);
      acc[1][nt] = __builtin_amdgcn_mfma_f32_16x16x32_bf16(a1, b, acc[1][nt], 0, 0, 0);
    }
  }
#pragma unroll
  for (int mt = 0; mt < 2; ++mt)
#pragma unroll
    for (int nt = 0; nt < 4; ++nt)
#pragma unroll
      for (int r = 0; r < 4; ++r) {
        int t = mt * 16 + quad * 4 + r;
        int d = w * 64 + nt * 16 + ml;
        kvr[(lbase + t) * 256 + d] = acc[mt][nt][r] * scl[t];
      }
}

// ---------------- Kernel G1: pos_out + combine + LN -> bf16 ----------------
__global__ void kernelG1(const float* __restrict__ m1c, const float* __restrict__ m1s,
                         const float* __restrict__ qc, const float* __restrict__ qs,
                         const float* __restrict__ kvr,
                         const float* __restrict__ w_mem1o, const float* __restrict__ b_mem1o,
                         const float* __restrict__ ln_g, const float* __restrict__ ln_b,
                         short* __restrict__ cbn) {
  __shared__ float pr[TG][P_];
  __shared__ float cb[TG][D_];
  __shared__ float mu_s[TG], rs_s[TG];
  int tid = threadIdx.x;
  int tok0 = blockIdx.x * TG;
  for (int pass = 0; pass < 2; ++pass) {
    int t = pass * 8 + tid / 32, p = tid % 32;
    int idx = (tok0 + t) * P_ + p;
    pr[t][p] = (m1c[idx] * qc[idx] + m1s[idx] * qs[idx]) * INV_SQRT_P;
  }
  __syncthreads();
  int d = tid;
  {
    float accs[TG];
    float bm = b_mem1o[d];
#pragma unroll
    for (int t = 0; t < TG; ++t) accs[t] = bm;
    for (int p = 0; p < P_; ++p) {
      float w = w_mem1o[p * D_ + d];
#pragma unroll
      for (int t = 0; t < TG; ++t) accs[t] += pr[t][p] * w;
    }
#pragma unroll
    for (int t = 0; t < TG; ++t) cb[t][d] = accs[t] + kvr[(tok0 + t) * D_ + d];
  }
  __syncthreads();
  {
    int t = tid >> 4, kg = tid & 15;
    float s = 0.f, s2 = 0.f;
#pragma unroll
    for (int i = 0; i < 16; ++i) {
      float v = cb[t][kg + 16 * i];
      s += v;
      s2 += v * v;
    }
#pragma unroll
    for (int m = 1; m < 16; m <<= 1) {
      s += __shfl_xor(s, m, 64);
      s2 += __shfl_xor(s2, m, 64);
    }
    if (kg == 0) {
      float mu = s / (float)D_;
      float var = s2 / (float)D_ - mu * mu;
      mu_s[t] = mu;
      rs_s[t] = rsqrtf(var + 1e-5f);
    }
  }
  __syncthreads();
  {
    float lg = ln_g[d], lb = ln_b[d];
#pragma unroll
    for (int t = 0; t < TG; ++t)
      cbn[(tok0 + t) * D_ + d] = f2bf((cb[t][d] - mu_s[t]) * rs_s[t] * lg + lb);
  }
}

extern "C" void kernel_launch(void* const* d_in, const int* in_sizes, int n_in,
                              void* d_out, int out_size, void* d_ws, size_t ws_size,
                              hipStream_t stream) {
  const float* x = (const float*)d_in[0];
  const float* pos = (const float*)d_in[1];
  const float* w_mem1v = (const float*)d_in[2];
  const float* b_mem1v = (const float*)d_in[3];
  const float* w_mem1o = (const float*)d_in[4];
  const float* b_mem1o = (const float*)d_in[5];
  const float* w_off = (const float*)d_in[6];
  const float* b_off = (const float*)d_in[7];
  const float* w_key = (const float*)d_in[8];
  const float* b_key = (const float*)d_in[9];
  const float* w_val = (const float*)d_in[10];
  const float* b_val = (const float*)d_in[11];
  const float* w_sk1 = (const float*)d_in[12];
  const float* b_sk1 = (const float*)d_in[13];
  const float* w_sk2 = (const float*)d_in[14];
  const float* b_sk2 = (const float*)d_in[15];
  const float* w_gate = (const float*)d_in[16];
  const float* b_gate = (const float*)d_in[17];
  const float* ln_g = (const float*)d_in[18];
  const float* ln_b = (const float*)d_in[19];
  const float* w_out = (const float*)d_in[20];
  const float* b_out = (const float*)d_in[21];
  float* out = (float*)d_out;
  float* ws = (float*)d_ws;

  const int BLP = B_ * L_ * P_;  // 262144
  const int BLD = B_ * L_ * D_;  // 2097152
  float* m1c = ws;
  float* m1s = m1c + BLP;
  float* qc = m1s + BLP;
  float* qs = qc + BLP;
  float* sg = qs + BLP;
  float* poff = sg + B_ * L_;
  // Y (8192*384 fp32) and U (B*NC*64*256 fp32 = 4.19M) share a region
  float* Y = poff + L_ * P_;
  float* U = Y;
  float* regC = U + (size_t)B_ * NC * 64 * D_;
  short* xbf = (short*)regC;            // BLD shorts
  short* ctxbf = xbf + BLD;             // BLD shorts
  float* kvr = regC;                    // aliases xbf+ctxbf (dead after gemm1)
  short* hs = ctxbf + BLD;
  short* gvT = hs + BLD;
  short* K2bf = gvT + BLD;              // B*L*64
  short* SPbf = K2bf + B_ * L_ * 64;    // B*L*64
  short* spT = SPbf + B_ * L_ * 64;     // B*NC*64*32
  short* cbn = spT + B_ * NC * 64 * 32;
  short* WA = cbn + BLD;
  short* W1 = WA + 384 * 256;
  short* WO = W1 + 256 * 512;
  short* W2T = WO + 256 * 256;

  wprep<<<3488, 256, 0, stream>>>(x, pos, w_val, w_mem1v, w_off, b_off, w_key, w_gate,
                                  w_sk1, w_out, w_sk2, WA, W1, WO, W2T, xbf, poff);
  gemm_k<2, 6, 0><<<128 * 6, 256, 0, stream>>>(xbf, nullptr, WA, nullptr, nullptr, Y, nullptr);
  kernelA3<<<(B_ * L_) / 8, 256, 0, stream>>>(Y, pos, poff, b_mem1v, b_key, b_gate, b_val,
                                              m1c, m1s, qc, qs, K2bf, gvT, sg);
  scan_all<<<260 + B_ * D_, 256, 0, stream>>>(m1c, m1s, sg, x, ctxbf);
  gemm_k<4, 4, 1><<<128 * 4, 256, 0, stream>>>(xbf, ctxbf, W1, b_sk1, nullptr, nullptr, hs);
  kernelC3m<<<(B_ * L_) / 64, 256, 0, stream>>>(hs, W2T, b_sk2, spT, SPbf);
  kernelD2<<<B_ * NC, 256, 0, stream>>>(spT, gvT, U);
  kernelE<<<(B_ * 64 * D_) / 256, 256, 0, stream>>>(U);
  kernelF2<<<B_ * NC, 256, 0, stream>>>(U, SPbf, K2bf, gvT, sg, kvr);
  kernelG1<<<(B_ * L_) / TG, 256, 0, stream>>>(m1c, m1s, qc, qs, kvr, w_mem1o, b_mem1o,
                                               ln_g, ln_b, cbn);
  gemm_k<2, 4, 2><<<128 * 4, 256, 0, stream>>>(cbn, nullptr, WO, b_out, x, out, nullptr);
}

// Round 6
// 193.798 us; speedup vs baseline: 2.0334x; 1.0447x over previous
//
#include <hip/hip_runtime.h>
#include <hip/hip_bf16.h>

constexpr int B_ = 4;
constexpr int L_ = 2048;
constexpr int D_ = 256;
constexpr int P_ = 32;
constexpr int CL = 32;   // chunk length for KV scan
constexpr int NC = L_ / CL;  // 64 chunks

#define PI_F 3.14159265358979323846f
#define INV_SQRT_P 0.17677669529663687f  // 1/sqrt(32)

typedef __attribute__((ext_vector_type(8))) short short8_t;
typedef __attribute__((ext_vector_type(4))) float floatx4;

static __device__ inline short f2bf(float f) {
  unsigned int u;
  __builtin_memcpy(&u, &f, 4);
  unsigned int r = (u + 0x7fffu + ((u >> 16) & 1u)) >> 16;
  return (short)r;
}

// ---------------- wprep: weight casts/transposes + x->bf16 + poff ----------
__global__ void wprep(const float* __restrict__ x, const float* __restrict__ pos,
                      const float* __restrict__ w_val, const float* __restrict__ w_mem1v,
                      const float* __restrict__ w_off, const float* __restrict__ b_off,
                      const float* __restrict__ w_key, const float* __restrict__ w_gate,
                      const float* __restrict__ w_sk1, const float* __restrict__ w_out,
                      const float* __restrict__ w_sk2, const float* __restrict__ w_mem1o,
                      short* __restrict__ WA, short* __restrict__ W1,
                      short* __restrict__ WO, short* __restrict__ W2T,
                      short* __restrict__ W1OT,
                      short* __restrict__ xbf, float* __restrict__ poff) {
  int blk = blockIdx.x, tid = threadIdx.x;
  if (blk < 384) {
    int idx = blk * 256 + tid;
    int n = idx >> 8, k = idx & 255;
    float v;
    if (n < 256) v = w_val[k * 256 + n];
    else if (n < 288) v = w_mem1v[k * 32 + (n - 256)];
    else if (n < 320) v = w_off[k * 32 + (n - 288)];
    else if (n < 352) v = w_key[k * 32 + (n - 320)];
    else if (n == 352) v = w_gate[k];
    else v = 0.f;
    WA[idx] = f2bf(v);
  } else if (blk < 896) {
    int idx = (blk - 384) * 256 + tid;
    int n = idx >> 9, k = idx & 511;
    W1[idx] = f2bf(w_sk1[k * 256 + n]);
  } else if (blk < 1152) {
    int idx = (blk - 896) * 256 + tid;
    int n = idx >> 8, k = idx & 255;
    WO[idx] = f2bf(w_out[k * 256 + n]);
  } else if (blk < 1184) {
    int idx = (blk - 1152) * 256 + tid;  // p*256 + k
    int p = idx >> 8, k = idx & 255;
    W2T[idx] = f2bf(w_sk2[k * 32 + p]);
  } else if (blk < 1216) {
    int idx = (blk - 1184) * 256 + tid;  // d*32 + p
    int d = idx >> 5, p = idx & 31;
    W1OT[idx] = f2bf(w_mem1o[p * 256 + d]);
  } else if (blk < 3264) {
    int idx = ((blk - 1216) * 256 + tid) * 4;
    float4 v = *(const float4*)&x[idx];
    short4 o;
    o.x = f2bf(v.x); o.y = f2bf(v.y); o.z = f2bf(v.z); o.w = f2bf(v.w);
    *(short4*)&xbf[idx] = o;
  } else {
    int idx = (blk - 3264) * 256 + tid;
    int l = idx >> 5, p = idx & 31;
    float a = b_off[p];
    for (int j = 0; j < 32; ++j) a += pos[l * 32 + j] * w_off[(256 + j) * 32 + p];
    poff[idx] = a;
  }
}

// ---------------- generic bf16 MFMA GEMM, 64x64 tile -----------------------
template <int KTILES, int NBLK, int MODE>
__global__ __launch_bounds__(256) void gemm_k(const short* __restrict__ A0,
                                              const short* __restrict__ A1,
                                              const short* __restrict__ W,
                                              const float* __restrict__ bias,
                                              const float* __restrict__ xres,
                                              float* __restrict__ outf,
                                              short* __restrict__ outb) {
  __shared__ short As[64][136];
  __shared__ short Bs[64][136];
  int tid = threadIdx.x;
  int mg = blockIdx.x / NBLK, ng = blockIdx.x % NBLK;
  int tok0 = mg * 64, n0 = ng * 64;
  int lane = tid & 63, w = tid >> 6;
  int mw = (w & 1) * 32, nw = (w >> 1) * 32;
  floatx4 acc[2][2] = {{{0.f, 0.f, 0.f, 0.f}, {0.f, 0.f, 0.f, 0.f}},
                       {{0.f, 0.f, 0.f, 0.f}, {0.f, 0.f, 0.f, 0.f}}};
  int r2 = tid >> 4, c8 = tid & 15;
  int ml = lane & 15, kq = (lane >> 4) * 8;
  const int K = KTILES * 128;

  for (int kt = 0; kt < KTILES; ++kt) {
    const short* Asrc;
    int cb;
    if (KTILES == 4) {
      Asrc = (kt < 2) ? A0 : A1;
      cb = (kt & 1) * 128;
    } else {
      Asrc = A0;
      cb = kt * 128;
    }
#pragma unroll
    for (int pass = 0; pass < 4; ++pass) {
      int row = pass * 16 + r2;
      *(short8_t*)&As[row][c8 * 8] =
          *(const short8_t*)&Asrc[(tok0 + row) * 256 + cb + c8 * 8];
      *(short8_t*)&Bs[row][c8 * 8] =
          *(const short8_t*)&W[(n0 + row) * K + kt * 128 + c8 * 8];
    }
    __syncthreads();
#pragma unroll
    for (int s = 0; s < 4; ++s) {
      short8_t a0 = *(short8_t*)&As[mw + ml][s * 32 + kq];
      short8_t a1 = *(short8_t*)&As[mw + 16 + ml][s * 32 + kq];
      short8_t b0 = *(short8_t*)&Bs[nw + ml][s * 32 + kq];
      short8_t b1 = *(short8_t*)&Bs[nw + 16 + ml][s * 32 + kq];
      acc[0][0] = __builtin_amdgcn_mfma_f32_16x16x32_bf16(a0, b0, acc[0][0], 0, 0, 0);
      acc[0][1] = __builtin_amdgcn_mfma_f32_16x16x32_bf16(a0, b1, acc[0][1], 0, 0, 0);
      acc[1][0] = __builtin_amdgcn_mfma_f32_16x16x32_bf16(a1, b0, acc[1][0], 0, 0, 0);
      acc[1][1] = __builtin_amdgcn_mfma_f32_16x16x32_bf16(a1, b1, acc[1][1], 0, 0, 0);
    }
    __syncthreads();
  }
  int col = lane & 15, rq = (lane >> 4) * 4;
#pragma unroll
  for (int nt = 0; nt < 2; ++nt) {
    int n = n0 + nw + nt * 16 + col;
    float bv = (MODE == 0) ? 0.f : bias[n];
#pragma unroll
    for (int mt = 0; mt < 2; ++mt) {
#pragma unroll
      for (int rg = 0; rg < 4; ++rg) {
        int tok = tok0 + mw + mt * 16 + rq + rg;
        float v = acc[mt][nt][rg] + bv;
        if (MODE == 0) {
          outf[tok * 384 + n] = v;
        } else if (MODE == 1) {
          float g = 0.5f * v * (1.f + erff(v * 0.70710678118654752f));
          outb[tok * 256 + n] = f2bf(g);
        } else {
          outf[tok * 256 + n] = xres[tok * 256 + n] + v;
        }
      }
    }
  }
}

// ---------------- Kernel A3: elementwise phasor prep from Y ----------------
__global__ void kernelA3(const float* __restrict__ Y, const float* __restrict__ pos,
                         const float* __restrict__ poff, const float* __restrict__ b_mem1v,
                         const float* __restrict__ b_key, const float* __restrict__ b_gate,
                         const float* __restrict__ b_val,
                         float* __restrict__ m1c, float* __restrict__ m1s,
                         float* __restrict__ qc, float* __restrict__ qs,
                         short* __restrict__ K2bf, short* __restrict__ gvT,
                         float* __restrict__ sg) {
  __shared__ float gsh[8];
  int tid = threadIdx.x;
  int tok0 = blockIdx.x * 8;
  int t = tid >> 5, p = tid & 31;
  int tok = tok0 + t, l = tok & (L_ - 1);
  float gate = 1.f / (1.f + expf(-(Y[tok * 384 + 352] + b_gate[0])));
  if (p == 0) {
    sg[tok] = gate;
    gsh[t] = gate;
  }
  float v1 = Y[tok * 384 + 256 + p] + b_mem1v[p];
  float ph = pos[l * 32 + p];
  float pc = cosf(ph), ps = sinf(ph);
  int idx = tok * 32 + p;
  m1c[idx] = pc * v1;
  m1s[idx] = ps * v1;
  float off = tanhf(Y[tok * 384 + 288 + p] + poff[l * 32 + p]) * PI_F;
  float oc = cosf(off), os = sinf(off);
  qc[idx] = pc * oc - ps * os;
  qs[idx] = ps * oc + pc * os;
  float kp = tanhf(Y[tok * 384 + 320 + p] + b_key[p]) * PI_F;
  K2bf[tok * 64 + p] = f2bf(cosf(kp));
  K2bf[tok * 64 + 32 + p] = f2bf(sinf(kp));
  __syncthreads();
  {
    int b = tok0 / L_;
    int l0 = tok0 & (L_ - 1);
    int bc = b * NC + (l0 >> 5);
    int tl0 = l0 & 31;
    short sv[8];
#pragma unroll
    for (int tt = 0; tt < 8; ++tt)
      sv[tt] = f2bf((Y[(tok0 + tt) * 384 + tid] + b_val[tid]) * gsh[tt]);
    *(short8_t*)&gvT[(bc * 256 + tid) * 32 + tl0] = *(short8_t*)sv;
  }
}

// ---------------- scan_all: fused scans ------------------------------------
__global__ void scan_all(float* __restrict__ m1c, float* __restrict__ m1s,
                         float* __restrict__ sg, const float* __restrict__ x,
                         short* __restrict__ ctxbf) {
  int blk = blockIdx.x;
  int tid = threadIdx.x, lane = tid & 63, wid = tid >> 6;
  __shared__ float wsum[4];
  float carry = 0.f;
  float* arr = nullptr;
  const float* src = nullptr;
  int base, inner, mode;
  if (blk < 256) {
    arr = (blk < 128) ? m1c : m1s;
    int row = blk & 127;
    int b = row >> 5, r = row & 31;
    base = b * L_ * P_ + r;
    inner = P_;
    mode = 0;
    src = arr;
  } else if (blk < 260) {
    arr = sg;
    base = (blk - 256) * L_;
    inner = 1;
    mode = 0;
    src = arr;
  } else {
    int row = blk - 260;
    int b = row >> 8, r = row & 255;
    base = b * L_ * D_ + r;
    inner = D_;
    mode = 1;
    src = x;
  }
  for (int t0 = 0; t0 < L_; t0 += 256) {
    int l = t0 + tid;
    float v = src[base + l * inner];
#pragma unroll
    for (int off = 1; off < 64; off <<= 1) {
      float n = __shfl_up(v, off, 64);
      if (lane >= off) v += n;
    }
    if (lane == 63) wsum[wid] = v;
    __syncthreads();
    float add = carry;
    for (int w = 0; w < wid; ++w) add += wsum[w];
    float res = v + add;
    if (mode == 0) arr[base + l * inner] = res;
    else ctxbf[base + l * inner] = f2bf(res / (float)(l + 1));
    carry += wsum[0] + wsum[1] + wsum[2] + wsum[3];
    __syncthreads();
  }
}

// ---------------- Kernel CD: storage phases (MFMA) + per-chunk U sums ------
// Block = 64 tokens = 2 chunks. Phase 1: sp = tanh(hs@w_sk2+b)*PI, write SPbf
// + SPL (LDS, A-frag layout). Phase 2: U_chunk[64,256] = SPL[q][t] x gvT.
__global__ __launch_bounds__(256) void kernelCD(const short* __restrict__ hs,
                                                const short* __restrict__ W2T,
                                                const float* __restrict__ b_sk2,
                                                const short* __restrict__ gvT,
                                                short* __restrict__ SPbf,
                                                float* __restrict__ U) {
  __shared__ __align__(16) short SPL[2][64][40];
  int tid = threadIdx.x;
  int tok0 = blockIdx.x * 64;
  int lane = tid & 63, w = tid >> 6;
  int ml = lane & 15, quad = lane >> 4, kq = quad * 8;
  int m0 = w * 16;
  floatx4 pacc[2] = {};
#pragma unroll
  for (int s = 0; s < 8; ++s) {
    short8_t a = *(const short8_t*)&hs[(tok0 + m0 + ml) * 256 + s * 32 + kq];
    short8_t b0 = *(const short8_t*)&W2T[ml * 256 + s * 32 + kq];
    short8_t b1 = *(const short8_t*)&W2T[(16 + ml) * 256 + s * 32 + kq];
    pacc[0] = __builtin_amdgcn_mfma_f32_16x16x32_bf16(a, b0, pacc[0], 0, 0, 0);
    pacc[1] = __builtin_amdgcn_mfma_f32_16x16x32_bf16(a, b1, pacc[1], 0, 0, 0);
  }
  int cl = w >> 1;
#pragma unroll
  for (int nt = 0; nt < 2; ++nt) {
    int p = nt * 16 + ml;
    float bs = b_sk2[p];
#pragma unroll
    for (int r = 0; r < 4; ++r) {
      int tok = tok0 + m0 + quad * 4 + r;
      float sp = tanhf(pacc[nt][r] + bs) * PI_F;
      short c = f2bf(cosf(sp)), s = f2bf(sinf(sp));
      int tl = (w & 1) * 16 + quad * 4 + r;
      SPL[cl][p][tl] = c;
      SPL[cl][32 + p][tl] = s;
      SPbf[tok * 64 + p] = c;
      SPbf[tok * 64 + 32 + p] = s;
    }
  }
  __syncthreads();
  // Phase 2: wave w -> chunk (w&1), d-half (w>>1)*128
  int c2 = w & 1, dbase = (w >> 1) * 128;
  int bc = blockIdx.x * 2 + c2;
  short8_t a[4];
#pragma unroll
  for (int mt = 0; mt < 4; ++mt) a[mt] = *(short8_t*)&SPL[c2][mt * 16 + ml][kq];
#pragma unroll
  for (int dp = 0; dp < 2; ++dp) {
    floatx4 acc[4][4] = {};
#pragma unroll
    for (int nt = 0; nt < 4; ++nt) {
      short8_t b = *(const short8_t*)&gvT[(bc * 256 + dbase + dp * 64 + nt * 16 + ml) * 32 + kq];
#pragma unroll
      for (int mt = 0; mt < 4; ++mt)
        acc[mt][nt] = __builtin_amdgcn_mfma_f32_16x16x32_bf16(a[mt], b, acc[mt][nt], 0, 0, 0);
    }
#pragma unroll
    for (int mt = 0; mt < 4; ++mt)
#pragma unroll
      for (int nt = 0; nt < 4; ++nt)
#pragma unroll
        for (int r = 0; r < 4; ++r) {
          int q = mt * 16 + quad * 4 + r;
          int d = dbase + dp * 64 + nt * 16 + ml;
          U[(bc * 64 + q) * 256 + d] = acc[mt][nt][r];
        }
  }
}

// ---------------- Kernel E: in-place exclusive prefix over chunks ----------
__global__ void kernelE(float* __restrict__ U) {
  int tid = blockIdx.x * 256 + threadIdx.x;  // B*64*D = 65536
  int d = tid % D_;
  int q = (tid / D_) % 64;
  int b = tid / (D_ * 64);
  int base = ((b * NC) * 64 + q) * D_ + d;
  const int cs = 64 * D_;
  float run = 0.f;
  for (int c0 = 0; c0 < NC; c0 += 8) {
    float v[8];
#pragma unroll
    for (int j = 0; j < 8; ++j) v[j] = U[base + (c0 + j) * cs];
#pragma unroll
    for (int j = 0; j < 8; ++j) {
      U[base + (c0 + j) * cs] = run;
      run += v[j];
    }
  }
}

// ---------------- Kernel FG: retrieval + pos_out + LN -> cbn ---------------
__global__ __launch_bounds__(256) void kernelFG(const float* __restrict__ U,
                                                const short* __restrict__ SPbf,
                                                const short* __restrict__ K2bf,
                                                const short* __restrict__ gvT,
                                                const float* __restrict__ sgc,
                                                const float* __restrict__ m1c,
                                                const float* __restrict__ m1s,
                                                const float* __restrict__ qc,
                                                const float* __restrict__ qs,
                                                const short* __restrict__ W1OT,
                                                const float* __restrict__ b_mem1o,
                                                const float* __restrict__ ln_g,
                                                const float* __restrict__ ln_b,
                                                short* __restrict__ cbn) {
  __shared__ __align__(16) short Ub[256][40];  // [d][q-half]
  __shared__ __align__(16) short SL[32][40];   // masked S [t][s]
  __shared__ __align__(16) short PR[32][40];   // pr [t][p]
  __shared__ float CMB[32][260];
  __shared__ float scl[32], mu_s[32], rs_s[32];
  int tid = threadIdx.x;
  int bc = blockIdx.x;
  int lbase = bc * CL;
  if (tid < 32) scl[tid] = rsqrtf(fmaxf(sgc[lbase + tid], 1.f)) * INV_SQRT_P;
  // stage Ub half 0 (q in [0,32))
  for (int it = 0; it < 8; ++it) {
    int idx = it * 256 + tid;
    int q = idx >> 6, d4 = idx & 63;
    float4 v = *(const float4*)&U[(bc * 64 + q) * 256 + d4 * 4];
    Ub[d4 * 4 + 0][q] = f2bf(v.x);
    Ub[d4 * 4 + 1][q] = f2bf(v.y);
    Ub[d4 * 4 + 2][q] = f2bf(v.z);
    Ub[d4 * 4 + 3][q] = f2bf(v.w);
  }
  // pr = (m1c*qc + m1s*qs)/sqrt(P), bf16 into PR[t][p]
  for (int it = 0; it < 4; ++it) {
    int i = it * 256 + tid;
    int g = lbase * 32 + i;
    PR[i >> 5][i & 31] = f2bf((m1c[g] * qc[g] + m1s[g] * qs[g]) * INV_SQRT_P);
  }
  __syncthreads();
  int lane = tid & 63, w = tid >> 6;
  int ml = lane & 15, quad = lane >> 4, kq = quad * 8;
  floatx4 acc[2][4] = {};
  short8_t ka0 = *(const short8_t*)&K2bf[(lbase + ml) * 64 + kq];
  short8_t ka1 = *(const short8_t*)&K2bf[(lbase + 16 + ml) * 64 + kq];
  short8_t kb0 = *(const short8_t*)&K2bf[(lbase + ml) * 64 + 32 + kq];
  short8_t kb1 = *(const short8_t*)&K2bf[(lbase + 16 + ml) * 64 + 32 + kq];
#pragma unroll
  for (int nt = 0; nt < 4; ++nt) {
    short8_t b = *(short8_t*)&Ub[w * 64 + nt * 16 + ml][kq];
    acc[0][nt] = __builtin_amdgcn_mfma_f32_16x16x32_bf16(ka0, b, acc[0][nt], 0, 0, 0);
    acc[1][nt] = __builtin_amdgcn_mfma_f32_16x16x32_bf16(ka1, b, acc[1][nt], 0, 0, 0);
  }
  if (w == 0) {
    floatx4 sacc[2][2] = {};
#pragma unroll
    for (int ks2 = 0; ks2 < 2; ++ks2) {
      short8_t a0 = (ks2 == 0) ? ka0 : kb0;
      short8_t a1 = (ks2 == 0) ? ka1 : kb1;
      short8_t b0 = *(const short8_t*)&SPbf[(lbase + ml) * 64 + ks2 * 32 + kq];
      short8_t b1 = *(const short8_t*)&SPbf[(lbase + 16 + ml) * 64 + ks2 * 32 + kq];
      sacc[0][0] = __builtin_amdgcn_mfma_f32_16x16x32_bf16(a0, b0, sacc[0][0], 0, 0, 0);
      sacc[0][1] = __builtin_amdgcn_mfma_f32_16x16x32_bf16(a0, b1, sacc[0][1], 0, 0, 0);
      sacc[1][0] = __builtin_amdgcn_mfma_f32_16x16x32_bf16(a1, b0, sacc[1][0], 0, 0, 0);
      sacc[1][1] = __builtin_amdgcn_mfma_f32_16x16x32_bf16(a1, b1, sacc[1][1], 0, 0, 0);
    }
#pragma unroll
    for (int mt = 0; mt < 2; ++mt)
#pragma unroll
      for (int nt = 0; nt < 2; ++nt)
#pragma unroll
        for (int r = 0; r < 4; ++r) {
          int trow = mt * 16 + quad * 4 + r;
          int scol = nt * 16 + ml;
          float v = (scol <= trow) ? sacc[mt][nt][r] : 0.f;
          SL[trow][scol] = f2bf(v);
        }
  }
  __syncthreads();
  // re-stage Ub half 1 (q in [32,64))
  for (int it = 0; it < 8; ++it) {
    int idx = it * 256 + tid;
    int q = idx >> 6, d4 = idx & 63;
    float4 v = *(const float4*)&U[(bc * 64 + 32 + q) * 256 + d4 * 4];
    Ub[d4 * 4 + 0][q] = f2bf(v.x);
    Ub[d4 * 4 + 1][q] = f2bf(v.y);
    Ub[d4 * 4 + 2][q] = f2bf(v.z);
    Ub[d4 * 4 + 3][q] = f2bf(v.w);
  }
  __syncthreads();
#pragma unroll
  for (int nt = 0; nt < 4; ++nt) {
    short8_t b = *(short8_t*)&Ub[w * 64 + nt * 16 + ml][kq];
    acc[0][nt] = __builtin_amdgcn_mfma_f32_16x16x32_bf16(kb0, b, acc[0][nt], 0, 0, 0);
    acc[1][nt] = __builtin_amdgcn_mfma_f32_16x16x32_bf16(kb1, b, acc[1][nt], 0, 0, 0);
  }
  {
    short8_t a0 = *(short8_t*)&SL[ml][kq];
    short8_t a1 = *(short8_t*)&SL[16 + ml][kq];
#pragma unroll
    for (int nt = 0; nt < 4; ++nt) {
      short8_t b = *(const short8_t*)&gvT[(bc * 256 + w * 64 + nt * 16 + ml) * 32 + kq];
      acc[0][nt] = __builtin_amdgcn_mfma_f32_16x16x32_bf16(a0, b, acc[0][nt], 0, 0, 0);
      acc[1][nt] = __builtin_amdgcn_mfma_f32_16x16x32_bf16(a1, b, acc[1][nt], 0, 0, 0);
    }
  }
  // pos_out MFMA: PR[t][p] @ W1OT[d][p]^T, K=32
  floatx4 macc[2][4] = {};
  {
    short8_t a0 = *(short8_t*)&PR[ml][kq];
    short8_t a1 = *(short8_t*)&PR[16 + ml][kq];
#pragma unroll
    for (int nt = 0; nt < 4; ++nt) {
      short8_t b = *(const short8_t*)&W1OT[(w * 64 + nt * 16 + ml) * 32 + kq];
      macc[0][nt] = __builtin_amdgcn_mfma_f32_16x16x32_bf16(a0, b, macc[0][nt], 0, 0, 0);
      macc[1][nt] = __builtin_amdgcn_mfma_f32_16x16x32_bf16(a1, b, macc[1][nt], 0, 0, 0);
    }
  }
  // combined -> LDS
#pragma unroll
  for (int mt = 0; mt < 2; ++mt)
#pragma unroll
    for (int nt = 0; nt < 4; ++nt) {
      int d = w * 64 + nt * 16 + ml;
      float bm = b_mem1o[d];
#pragma unroll
      for (int r = 0; r < 4; ++r) {
        int t = mt * 16 + quad * 4 + r;
        CMB[t][d] = acc[mt][nt][r] * scl[t] + macc[mt][nt][r] + bm;
      }
    }
  __syncthreads();
  // LN stats: thread (t = tid/8, g = tid%8), stride-8 slices
  {
    int t = tid >> 3, g = tid & 7;
    float s = 0.f, s2 = 0.f;
#pragma unroll
    for (int j = 0; j < 32; ++j) {
      float v = CMB[t][g + j * 8];
      s += v;
      s2 += v * v;
    }
#pragma unroll
    for (int m = 1; m < 8; m <<= 1) {
      s += __shfl_xor(s, m, 64);
      s2 += __shfl_xor(s2, m, 64);
    }
    if (g == 0) {
      float mu = s / (float)D_;
      float var = s2 / (float)D_ - mu * mu;
      mu_s[t] = mu;
      rs_s[t] = rsqrtf(var + 1e-5f);
    }
  }
  __syncthreads();
  {
    float lg = ln_g[tid], lb = ln_b[tid];
#pragma unroll
    for (int t = 0; t < 32; ++t)
      cbn[(lbase + t) * 256 + tid] = f2bf((CMB[t][tid] - mu_s[t]) * rs_s[t] * lg + lb);
  }
}

extern "C" void kernel_launch(void* const* d_in, const int* in_sizes, int n_in,
                              void* d_out, int out_size, void* d_ws, size_t ws_size,
                              hipStream_t stream) {
  const float* x = (const float*)d_in[0];
  const float* pos = (const float*)d_in[1];
  const float* w_mem1v = (const float*)d_in[2];
  const float* b_mem1v = (const float*)d_in[3];
  const float* w_mem1o = (const float*)d_in[4];
  const float* b_mem1o = (const float*)d_in[5];
  const float* w_off = (const float*)d_in[6];
  const float* b_off = (const float*)d_in[7];
  const float* w_key = (const float*)d_in[8];
  const float* b_key = (const float*)d_in[9];
  const float* w_val = (const float*)d_in[10];
  const float* b_val = (const float*)d_in[11];
  const float* w_sk1 = (const float*)d_in[12];
  const float* b_sk1 = (const float*)d_in[13];
  const float* w_sk2 = (const float*)d_in[14];
  const float* b_sk2 = (const float*)d_in[15];
  const float* w_gate = (const float*)d_in[16];
  const float* b_gate = (const float*)d_in[17];
  const float* ln_g = (const float*)d_in[18];
  const float* ln_b = (const float*)d_in[19];
  const float* w_out = (const float*)d_in[20];
  const float* b_out = (const float*)d_in[21];
  float* out = (float*)d_out;
  float* ws = (float*)d_ws;

  const int BLP = B_ * L_ * P_;  // 262144
  const int BLD = B_ * L_ * D_;  // 2097152
  float* m1c = ws;
  float* m1s = m1c + BLP;
  float* qc = m1s + BLP;
  float* qs = qc + BLP;
  float* sg = qs + BLP;
  float* poff = sg + B_ * L_;
  // Y (8192*384 fp32) and U (B*NC*64*256 fp32 = 4.19M) share a region
  float* Y = poff + L_ * P_;
  float* U = Y;
  short* xbf = (short*)(U + (size_t)B_ * NC * 64 * D_);  // BLD shorts
  short* cbn = xbf;                   // aliases xbf (dead after gemm1)
  short* ctxbf = xbf + BLD;
  short* hs = ctxbf + BLD;
  short* gvT = hs + BLD;
  short* K2bf = gvT + BLD;            // B*L*64
  short* SPbf = K2bf + B_ * L_ * 64;  // B*L*64
  short* WA = SPbf + B_ * L_ * 64;
  short* W1 = WA + 384 * 256;
  short* WO = W1 + 256 * 512;
  short* W2T = WO + 256 * 256;
  short* W1OT = W2T + 32 * 256;

  wprep<<<3520, 256, 0, stream>>>(x, pos, w_val, w_mem1v, w_off, b_off, w_key, w_gate,
                                  w_sk1, w_out, w_sk2, w_mem1o, WA, W1, WO, W2T, W1OT,
                                  xbf, poff);
  gemm_k<2, 6, 0><<<128 * 6, 256, 0, stream>>>(xbf, nullptr, WA, nullptr, nullptr, Y, nullptr);
  kernelA3<<<(B_ * L_) / 8, 256, 0, stream>>>(Y, pos, poff, b_mem1v, b_key, b_gate, b_val,
                                              m1c, m1s, qc, qs, K2bf, gvT, sg);
  scan_all<<<260 + B_ * D_, 256, 0, stream>>>(m1c, m1s, sg, x, ctxbf);
  gemm_k<4, 4, 1><<<128 * 4, 256, 0, stream>>>(xbf, ctxbf, W1, b_sk1, nullptr, nullptr, hs);
  kernelCD<<<(B_ * L_) / 64, 256, 0, stream>>>(hs, W2T, b_sk2, gvT, SPbf, U);
  kernelE<<<(B_ * 64 * D_) / 256, 256, 0, stream>>>(U);
  kernelFG<<<B_ * NC, 256, 0, stream>>>(U, SPbf, K2bf, gvT, sg, m1c, m1s, qc, qs,
                                        W1OT, b_mem1o, ln_g, ln_b, cbn);
  gemm_k<2, 4, 2><<<128 * 4, 256, 0, stream>>>(cbn, nullptr, WO, b_out, x, out, nullptr);
}

// Round 7
// 190.562 us; speedup vs baseline: 2.0679x; 1.0170x over previous
//
#include <hip/hip_runtime.h>
#include <hip/hip_bf16.h>

constexpr int B_ = 4;
constexpr int L_ = 2048;
constexpr int D_ = 256;
constexpr int P_ = 32;
constexpr int CL = 32;   // chunk length for KV scan
constexpr int NC = L_ / CL;  // 64 chunks

#define PI_F 3.14159265358979323846f
#define INV_SQRT_P 0.17677669529663687f  // 1/sqrt(32)

typedef __attribute__((ext_vector_type(8))) short short8_t;
typedef __attribute__((ext_vector_type(4))) float floatx4;

static __device__ inline short f2bf(float f) {
  unsigned int u;
  __builtin_memcpy(&u, &f, 4);
  unsigned int r = (u + 0x7fffu + ((u >> 16) & 1u)) >> 16;
  return (short)r;
}
static __device__ inline float bf2f(short s) {
  unsigned int u = ((unsigned int)(unsigned short)s) << 16;
  float f;
  __builtin_memcpy(&f, &u, 4);
  return f;
}

// ---------------- wprep: weight casts/transposes + x->bf16 + poff ----------
__global__ void wprep(const float* __restrict__ x, const float* __restrict__ pos,
                      const float* __restrict__ w_val, const float* __restrict__ w_mem1v,
                      const float* __restrict__ w_off, const float* __restrict__ b_off,
                      const float* __restrict__ w_key, const float* __restrict__ w_gate,
                      const float* __restrict__ w_sk1, const float* __restrict__ w_out,
                      const float* __restrict__ w_sk2, const float* __restrict__ w_mem1o,
                      short* __restrict__ WA, short* __restrict__ W1,
                      short* __restrict__ WO, short* __restrict__ W2T,
                      short* __restrict__ W1OT,
                      short* __restrict__ xbf, float* __restrict__ poff) {
  int blk = blockIdx.x, tid = threadIdx.x;
  if (blk < 384) {
    int idx = blk * 256 + tid;
    int n = idx >> 8, k = idx & 255;
    float v;
    if (n < 256) v = w_val[k * 256 + n];
    else if (n < 288) v = w_mem1v[k * 32 + (n - 256)];
    else if (n < 320) v = w_off[k * 32 + (n - 288)];
    else if (n < 352) v = w_key[k * 32 + (n - 320)];
    else if (n == 352) v = w_gate[k];
    else v = 0.f;
    WA[idx] = f2bf(v);
  } else if (blk < 896) {
    int idx = (blk - 384) * 256 + tid;
    int n = idx >> 9, k = idx & 511;
    W1[idx] = f2bf(w_sk1[k * 256 + n]);
  } else if (blk < 1152) {
    int idx = (blk - 896) * 256 + tid;
    int n = idx >> 8, k = idx & 255;
    WO[idx] = f2bf(w_out[k * 256 + n]);
  } else if (blk < 1184) {
    int idx = (blk - 1152) * 256 + tid;  // p*256 + k
    int p = idx >> 8, k = idx & 255;
    W2T[idx] = f2bf(w_sk2[k * 32 + p]);
  } else if (blk < 1216) {
    int idx = (blk - 1184) * 256 + tid;  // d*32 + p
    int d = idx >> 5, p = idx & 31;
    W1OT[idx] = f2bf(w_mem1o[p * 256 + d]);
  } else if (blk < 3264) {
    int idx = ((blk - 1216) * 256 + tid) * 4;
    float4 v = *(const float4*)&x[idx];
    short4 o;
    o.x = f2bf(v.x); o.y = f2bf(v.y); o.z = f2bf(v.z); o.w = f2bf(v.w);
    *(short4*)&xbf[idx] = o;
  } else {
    int idx = (blk - 3264) * 256 + tid;
    int l = idx >> 5, p = idx & 31;
    float a = b_off[p];
    for (int j = 0; j < 32; ++j) a += pos[l * 32 + j] * w_off[(256 + j) * 32 + p];
    poff[idx] = a;
  }
}

// ---------------- generic bf16 MFMA GEMM, 64x64 tile -----------------------
// MODE 0: Y bf16 [8192,384] = A0 @ W (no bias)
// MODE 1: hs bf16 = gelu(A @ W + bias)
// MODE 2: out fp32 = xres + A0 @ W + bias
template <int KTILES, int NBLK, int MODE>
__global__ __launch_bounds__(256) void gemm_k(const short* __restrict__ A0,
                                              const short* __restrict__ A1,
                                              const short* __restrict__ W,
                                              const float* __restrict__ bias,
                                              const float* __restrict__ xres,
                                              float* __restrict__ outf,
                                              short* __restrict__ outb) {
  __shared__ short As[64][136];
  __shared__ short Bs[64][136];
  int tid = threadIdx.x;
  int mg = blockIdx.x / NBLK, ng = blockIdx.x % NBLK;
  int tok0 = mg * 64, n0 = ng * 64;
  int lane = tid & 63, w = tid >> 6;
  int mw = (w & 1) * 32, nw = (w >> 1) * 32;
  floatx4 acc[2][2] = {{{0.f, 0.f, 0.f, 0.f}, {0.f, 0.f, 0.f, 0.f}},
                       {{0.f, 0.f, 0.f, 0.f}, {0.f, 0.f, 0.f, 0.f}}};
  int r2 = tid >> 4, c8 = tid & 15;
  int ml = lane & 15, kq = (lane >> 4) * 8;
  const int K = KTILES * 128;

  for (int kt = 0; kt < KTILES; ++kt) {
    const short* Asrc;
    int cb;
    if (KTILES == 4) {
      Asrc = (kt < 2) ? A0 : A1;
      cb = (kt & 1) * 128;
    } else {
      Asrc = A0;
      cb = kt * 128;
    }
#pragma unroll
    for (int pass = 0; pass < 4; ++pass) {
      int row = pass * 16 + r2;
      *(short8_t*)&As[row][c8 * 8] =
          *(const short8_t*)&Asrc[(tok0 + row) * 256 + cb + c8 * 8];
      *(short8_t*)&Bs[row][c8 * 8] =
          *(const short8_t*)&W[(n0 + row) * K + kt * 128 + c8 * 8];
    }
    __syncthreads();
#pragma unroll
    for (int s = 0; s < 4; ++s) {
      short8_t a0 = *(short8_t*)&As[mw + ml][s * 32 + kq];
      short8_t a1 = *(short8_t*)&As[mw + 16 + ml][s * 32 + kq];
      short8_t b0 = *(short8_t*)&Bs[nw + ml][s * 32 + kq];
      short8_t b1 = *(short8_t*)&Bs[nw + 16 + ml][s * 32 + kq];
      acc[0][0] = __builtin_amdgcn_mfma_f32_16x16x32_bf16(a0, b0, acc[0][0], 0, 0, 0);
      acc[0][1] = __builtin_amdgcn_mfma_f32_16x16x32_bf16(a0, b1, acc[0][1], 0, 0, 0);
      acc[1][0] = __builtin_amdgcn_mfma_f32_16x16x32_bf16(a1, b0, acc[1][0], 0, 0, 0);
      acc[1][1] = __builtin_amdgcn_mfma_f32_16x16x32_bf16(a1, b1, acc[1][1], 0, 0, 0);
    }
    __syncthreads();
  }
  int col = lane & 15, rq = (lane >> 4) * 4;
#pragma unroll
  for (int nt = 0; nt < 2; ++nt) {
    int n = n0 + nw + nt * 16 + col;
    float bv = (MODE == 0) ? 0.f : bias[n];
#pragma unroll
    for (int mt = 0; mt < 2; ++mt) {
#pragma unroll
      for (int rg = 0; rg < 4; ++rg) {
        int tok = tok0 + mw + mt * 16 + rq + rg;
        float v = acc[mt][nt][rg] + bv;
        if (MODE == 0) {
          outb[tok * 384 + n] = f2bf(v);
        } else if (MODE == 1) {
          float g = 0.5f * v * (1.f + erff(v * 0.70710678118654752f));
          outb[tok * 256 + n] = f2bf(g);
        } else {
          outf[tok * 256 + n] = xres[tok * 256 + n] + v;
        }
      }
    }
  }
}

// ---------------- Kernel A3: elementwise phasor prep from Ybf --------------
// m1cT/m1sT transposed [b][p][l] for coalesced scan; qc/qs in [tok][p].
__global__ void kernelA3(const short* __restrict__ Ybf, const float* __restrict__ pos,
                         const float* __restrict__ poff, const float* __restrict__ b_mem1v,
                         const float* __restrict__ b_key, const float* __restrict__ b_gate,
                         const float* __restrict__ b_val,
                         float* __restrict__ m1cT, float* __restrict__ m1sT,
                         float* __restrict__ qc, float* __restrict__ qs,
                         short* __restrict__ K2bf, short* __restrict__ gvT,
                         float* __restrict__ sg) {
  __shared__ float gsh[8];
  int tid = threadIdx.x;
  int tok0 = blockIdx.x * 8;
  int t = tid >> 5, p = tid & 31;
  int tok = tok0 + t, l = tok & (L_ - 1);
  int b = tok >> 11;
  float gate = 1.f / (1.f + expf(-(bf2f(Ybf[tok * 384 + 352]) + b_gate[0])));
  if (p == 0) {
    sg[tok] = gate;
    gsh[t] = gate;
  }
  float v1 = bf2f(Ybf[tok * 384 + 256 + p]) + b_mem1v[p];
  float ph = pos[l * 32 + p];
  float pc = cosf(ph), ps = sinf(ph);
  int idxT = (b * 32 + p) * L_ + l;
  m1cT[idxT] = pc * v1;
  m1sT[idxT] = ps * v1;
  float off = tanhf(bf2f(Ybf[tok * 384 + 288 + p]) + poff[l * 32 + p]) * PI_F;
  float oc = cosf(off), os = sinf(off);
  int idx = tok * 32 + p;
  qc[idx] = pc * oc - ps * os;
  qs[idx] = ps * oc + pc * os;
  float kp = tanhf(bf2f(Ybf[tok * 384 + 320 + p]) + b_key[p]) * PI_F;
  K2bf[tok * 64 + p] = f2bf(cosf(kp));
  K2bf[tok * 64 + 32 + p] = f2bf(sinf(kp));
  __syncthreads();
  {
    int l0 = tok0 & (L_ - 1);
    int bc = (tok0 >> 11) * NC + (l0 >> 5);
    int tl0 = l0 & 31;
    short sv[8];
#pragma unroll
    for (int tt = 0; tt < 8; ++tt)
      sv[tt] = f2bf((bf2f(Ybf[(tok0 + tt) * 384 + tid]) + b_val[tid]) * gsh[tt]);
    *(short8_t*)&gvT[(bc * 256 + tid) * 32 + tl0] = *(short8_t*)sv;
  }
}

// ---------------- scan_all: m1 scans (coalesced) + sg + ctx chunk sums -----
// blk<128: m1cT row; blk<256: m1sT row; blk<260: sg; blk<516: ctx chunk sums.
__global__ void scan_all(float* __restrict__ m1cT, float* __restrict__ m1sT,
                         float* __restrict__ sg, const float* __restrict__ x,
                         float* __restrict__ ctxsum) {
  int blk = blockIdx.x;
  int tid = threadIdx.x;
  if (blk >= 260) {
    // ctx chunk sums: block = (b, chunk of 32 tokens), thread = d (coalesced)
    int c2 = blk - 260;
    int b = c2 >> 6, ch = c2 & 63;
    int xb = (b * L_ + ch * 32) * 256 + tid;
    float s = 0.f;
#pragma unroll 8
    for (int i = 0; i < 32; ++i) s += x[xb + i * 256];
    ctxsum[c2 * 256 + tid] = s;
    return;
  }
  int lane = tid & 63, wid = tid >> 6;
  __shared__ float wsum[4];
  float carry = 0.f;
  float* arr;
  int base;
  if (blk < 256) {
    arr = (blk < 128) ? m1cT : m1sT;
    base = (blk & 127) * L_;
  } else {
    arr = sg;
    base = (blk - 256) * L_;
  }
  for (int t0 = 0; t0 < L_; t0 += 256) {
    int l = t0 + tid;
    float v = arr[base + l];
#pragma unroll
    for (int off = 1; off < 64; off <<= 1) {
      float n = __shfl_up(v, off, 64);
      if (lane >= off) v += n;
    }
    if (lane == 63) wsum[wid] = v;
    __syncthreads();
    float add = carry;
    for (int w = 0; w < wid; ++w) add += wsum[w];
    arr[base + l] = v + add;
    carry += wsum[0] + wsum[1] + wsum[2] + wsum[3];
    __syncthreads();
  }
}

// ---------------- kernelCtx: local ctx scan + chunk prefix -> ctxbf --------
__global__ void kernelCtx(const float* __restrict__ x, const float* __restrict__ ctxsum,
                          short* __restrict__ ctxbf) {
  int c2 = blockIdx.x;
  int b = c2 >> 6, ch = c2 & 63;
  int tid = threadIdx.x;
  float run = 0.f;
  int sb = b * 64 * 256 + tid;
  for (int c = 0; c < ch; ++c) run += ctxsum[sb + c * 256];
  int xb = (b * L_ + ch * 32) * 256 + tid;
#pragma unroll 8
  for (int i = 0; i < 32; ++i) {
    run += x[xb + i * 256];
    int l = ch * 32 + i;
    ctxbf[xb + i * 256] = f2bf(run / (float)(l + 1));
  }
}

// ---------------- Kernel CD: storage phases (MFMA) + per-chunk U sums ------
// Writes SPbf [tok][64] and UT bf16 [bc][d][q] (pre-transposed for E/FG).
__global__ __launch_bounds__(256) void kernelCD(const short* __restrict__ hs,
                                                const short* __restrict__ W2T,
                                                const float* __restrict__ b_sk2,
                                                const short* __restrict__ gvT,
                                                short* __restrict__ SPbf,
                                                short* __restrict__ UT) {
  __shared__ __align__(16) short SPL[2][64][40];
  int tid = threadIdx.x;
  int tok0 = blockIdx.x * 64;
  int lane = tid & 63, w = tid >> 6;
  int ml = lane & 15, quad = lane >> 4, kq = quad * 8;
  int m0 = w * 16;
  floatx4 pacc[2] = {};
#pragma unroll
  for (int s = 0; s < 8; ++s) {
    short8_t a = *(const short8_t*)&hs[(tok0 + m0 + ml) * 256 + s * 32 + kq];
    short8_t b0 = *(const short8_t*)&W2T[ml * 256 + s * 32 + kq];
    short8_t b1 = *(const short8_t*)&W2T[(16 + ml) * 256 + s * 32 + kq];
    pacc[0] = __builtin_amdgcn_mfma_f32_16x16x32_bf16(a, b0, pacc[0], 0, 0, 0);
    pacc[1] = __builtin_amdgcn_mfma_f32_16x16x32_bf16(a, b1, pacc[1], 0, 0, 0);
  }
  int cl = w >> 1;
#pragma unroll
  for (int nt = 0; nt < 2; ++nt) {
    int p = nt * 16 + ml;
    float bs = b_sk2[p];
#pragma unroll
    for (int r = 0; r < 4; ++r) {
      int tok = tok0 + m0 + quad * 4 + r;
      float sp = tanhf(pacc[nt][r] + bs) * PI_F;
      short c = f2bf(cosf(sp)), s = f2bf(sinf(sp));
      int tl = (w & 1) * 16 + quad * 4 + r;
      SPL[cl][p][tl] = c;
      SPL[cl][32 + p][tl] = s;
      SPbf[tok * 64 + p] = c;
      SPbf[tok * 64 + 32 + p] = s;
    }
  }
  __syncthreads();
  int c2 = w & 1, dbase = (w >> 1) * 128;
  int bc = blockIdx.x * 2 + c2;
  short8_t a[4];
#pragma unroll
  for (int mt = 0; mt < 4; ++mt) a[mt] = *(short8_t*)&SPL[c2][mt * 16 + ml][kq];
#pragma unroll
  for (int dp = 0; dp < 2; ++dp) {
    floatx4 acc[4][4] = {};
#pragma unroll
    for (int nt = 0; nt < 4; ++nt) {
      short8_t b = *(const short8_t*)&gvT[(bc * 256 + dbase + dp * 64 + nt * 16 + ml) * 32 + kq];
#pragma unroll
      for (int mt = 0; mt < 4; ++mt)
        acc[mt][nt] = __builtin_amdgcn_mfma_f32_16x16x32_bf16(a[mt], b, acc[mt][nt], 0, 0, 0);
    }
#pragma unroll
    for (int mt = 0; mt < 4; ++mt)
#pragma unroll
      for (int nt = 0; nt < 4; ++nt)
#pragma unroll
        for (int r = 0; r < 4; ++r) {
          int q = mt * 16 + quad * 4 + r;
          int d = dbase + dp * 64 + nt * 16 + ml;
          UT[(bc * 256 + d) * 64 + q] = f2bf(acc[mt][nt][r]);
        }
  }
}

// ---------------- Kernel E: in-place exclusive prefix over chunks (bf16) ---
__global__ void kernelE(short* __restrict__ UT) {
  int tid = blockIdx.x * 256 + threadIdx.x;  // B*256d*64q = 65536
  int q = tid & 63;
  int d = (tid >> 6) & 255;
  int b = tid >> 14;
  int base = ((b * NC) * 256 + d) * 64 + q;
  const int cs = 256 * 64;
  float run = 0.f;
  for (int c0 = 0; c0 < NC; c0 += 8) {
    short v[8];
#pragma unroll
    for (int j = 0; j < 8; ++j) v[j] = UT[base + (c0 + j) * cs];
#pragma unroll
    for (int j = 0; j < 8; ++j) {
      UT[base + (c0 + j) * cs] = f2bf(run);
      run += bf2f(v[j]);
    }
  }
}

// ---------------- Kernel FG: retrieval + pos_out + LN -> cbn ---------------
// U B-frags load directly from UT (global, bf16, pre-transposed) — no staging.
__global__ __launch_bounds__(256) void kernelFG(const short* __restrict__ UT,
                                                const short* __restrict__ SPbf,
                                                const short* __restrict__ K2bf,
                                                const short* __restrict__ gvT,
                                                const float* __restrict__ sgc,
                                                const float* __restrict__ m1cT,
                                                const float* __restrict__ m1sT,
                                                const float* __restrict__ qc,
                                                const float* __restrict__ qs,
                                                const short* __restrict__ W1OT,
                                                const float* __restrict__ b_mem1o,
                                                const float* __restrict__ ln_g,
                                                const float* __restrict__ ln_b,
                                                short* __restrict__ cbn) {
  __shared__ __align__(16) short SL[32][40];   // masked S [t][s]
  __shared__ __align__(16) short PR[32][40];   // pr [t][p]
  __shared__ float CMB[32][260];
  __shared__ float scl[32], mu_s[32], rs_s[32];
  int tid = threadIdx.x;
  int bc = blockIdx.x;
  int lbase = bc * CL;
  int bb = bc >> 6, lloc = (bc & 63) * 32;
  if (tid < 32) scl[tid] = rsqrtf(fmaxf(sgc[lbase + tid], 1.f)) * INV_SQRT_P;
  // pr = (m1c*qc + m1s*qs)/sqrt(P), bf16 into PR[t][p]
  for (int it = 0; it < 4; ++it) {
    int i = it * 256 + tid;
    int p = i >> 5, t = i & 31;
    int gT = (bb * 32 + p) * L_ + lloc + t;
    int g = (lbase + t) * 32 + p;
    PR[t][p] = f2bf((m1cT[gT] * qc[g] + m1sT[gT] * qs[g]) * INV_SQRT_P);
  }
  int lane = tid & 63, w = tid >> 6;
  int ml = lane & 15, quad = lane >> 4, kq = quad * 8;
  floatx4 acc[2][4] = {};
  short8_t ka0 = *(const short8_t*)&K2bf[(lbase + ml) * 64 + kq];
  short8_t ka1 = *(const short8_t*)&K2bf[(lbase + 16 + ml) * 64 + kq];
  short8_t kb0 = *(const short8_t*)&K2bf[(lbase + ml) * 64 + 32 + kq];
  short8_t kb1 = *(const short8_t*)&K2bf[(lbase + 16 + ml) * 64 + 32 + kq];
  // Part 1, ks=0: K2[:,0:32] @ Uprev[0:32,:]  (B-frag from UT global)
#pragma unroll
  for (int nt = 0; nt < 4; ++nt) {
    short8_t b = *(const short8_t*)&UT[(bc * 256 + w * 64 + nt * 16 + ml) * 64 + kq];
    acc[0][nt] = __builtin_amdgcn_mfma_f32_16x16x32_bf16(ka0, b, acc[0][nt], 0, 0, 0);
    acc[1][nt] = __builtin_amdgcn_mfma_f32_16x16x32_bf16(ka1, b, acc[1][nt], 0, 0, 0);
  }
  // wave 0: S = K2 @ SP^T, mask, write SL[t][s]
  if (w == 0) {
    floatx4 sacc[2][2] = {};
#pragma unroll
    for (int ks2 = 0; ks2 < 2; ++ks2) {
      short8_t a0 = (ks2 == 0) ? ka0 : kb0;
      short8_t a1 = (ks2 == 0) ? ka1 : kb1;
      short8_t b0 = *(const short8_t*)&SPbf[(lbase + ml) * 64 + ks2 * 32 + kq];
      short8_t b1 = *(const short8_t*)&SPbf[(lbase + 16 + ml) * 64 + ks2 * 32 + kq];
      sacc[0][0] = __builtin_amdgcn_mfma_f32_16x16x32_bf16(a0, b0, sacc[0][0], 0, 0, 0);
      sacc[0][1] = __builtin_amdgcn_mfma_f32_16x16x32_bf16(a0, b1, sacc[0][1], 0, 0, 0);
      sacc[1][0] = __builtin_amdgcn_mfma_f32_16x16x32_bf16(a1, b0, sacc[1][0], 0, 0, 0);
      sacc[1][1] = __builtin_amdgcn_mfma_f32_16x16x32_bf16(a1, b1, sacc[1][1], 0, 0, 0);
    }
#pragma unroll
    for (int mt = 0; mt < 2; ++mt)
#pragma unroll
      for (int nt = 0; nt < 2; ++nt)
#pragma unroll
        for (int r = 0; r < 4; ++r) {
          int trow = mt * 16 + quad * 4 + r;
          int scol = nt * 16 + ml;
          float v = (scol <= trow) ? sacc[mt][nt][r] : 0.f;
          SL[trow][scol] = f2bf(v);
        }
  }
  __syncthreads();
  // Part 1, ks=1: K2[:,32:64] @ Uprev[32:64,:]
#pragma unroll
  for (int nt = 0; nt < 4; ++nt) {
    short8_t b = *(const short8_t*)&UT[(bc * 256 + w * 64 + nt * 16 + ml) * 64 + 32 + kq];
    acc[0][nt] = __builtin_amdgcn_mfma_f32_16x16x32_bf16(kb0, b, acc[0][nt], 0, 0, 0);
    acc[1][nt] = __builtin_amdgcn_mfma_f32_16x16x32_bf16(kb1, b, acc[1][nt], 0, 0, 0);
  }
  // Part 2: S @ gv
  {
    short8_t a0 = *(short8_t*)&SL[ml][kq];
    short8_t a1 = *(short8_t*)&SL[16 + ml][kq];
#pragma unroll
    for (int nt = 0; nt < 4; ++nt) {
      short8_t b = *(const short8_t*)&gvT[(bc * 256 + w * 64 + nt * 16 + ml) * 32 + kq];
      acc[0][nt] = __builtin_amdgcn_mfma_f32_16x16x32_bf16(a0, b, acc[0][nt], 0, 0, 0);
      acc[1][nt] = __builtin_amdgcn_mfma_f32_16x16x32_bf16(a1, b, acc[1][nt], 0, 0, 0);
    }
  }
  // pos_out MFMA: PR[t][p] @ W1OT[d][p]^T, K=32
  floatx4 macc[2][4] = {};
  {
    short8_t a0 = *(short8_t*)&PR[ml][kq];
    short8_t a1 = *(short8_t*)&PR[16 + ml][kq];
#pragma unroll
    for (int nt = 0; nt < 4; ++nt) {
      short8_t b = *(const short8_t*)&W1OT[(w * 64 + nt * 16 + ml) * 32 + kq];
      macc[0][nt] = __builtin_amdgcn_mfma_f32_16x16x32_bf16(a0, b, macc[0][nt], 0, 0, 0);
      macc[1][nt] = __builtin_amdgcn_mfma_f32_16x16x32_bf16(a1, b, macc[1][nt], 0, 0, 0);
    }
  }
#pragma unroll
  for (int mt = 0; mt < 2; ++mt)
#pragma unroll
    for (int nt = 0; nt < 4; ++nt) {
      int d = w * 64 + nt * 16 + ml;
      float bm = b_mem1o[d];
#pragma unroll
      for (int r = 0; r < 4; ++r) {
        int t = mt * 16 + quad * 4 + r;
        CMB[t][d] = acc[mt][nt][r] * scl[t] + macc[mt][nt][r] + bm;
      }
    }
  __syncthreads();
  {
    int t = tid >> 3, g = tid & 7;
    float s = 0.f, s2 = 0.f;
#pragma unroll
    for (int j = 0; j < 32; ++j) {
      float v = CMB[t][g + j * 8];
      s += v;
      s2 += v * v;
    }
#pragma unroll
    for (int m = 1; m < 8; m <<= 1) {
      s += __shfl_xor(s, m, 64);
      s2 += __shfl_xor(s2, m, 64);
    }
    if (g == 0) {
      float mu = s / (float)D_;
      float var = s2 / (float)D_ - mu * mu;
      mu_s[t] = mu;
      rs_s[t] = rsqrtf(var + 1e-5f);
    }
  }
  __syncthreads();
  {
    float lg = ln_g[tid], lb = ln_b[tid];
#pragma unroll
    for (int t = 0; t < 32; ++t)
      cbn[(lbase + t) * 256 + tid] = f2bf((CMB[t][tid] - mu_s[t]) * rs_s[t] * lg + lb);
  }
}

extern "C" void kernel_launch(void* const* d_in, const int* in_sizes, int n_in,
                              void* d_out, int out_size, void* d_ws, size_t ws_size,
                              hipStream_t stream) {
  const float* x = (const float*)d_in[0];
  const float* pos = (const float*)d_in[1];
  const float* w_mem1v = (const float*)d_in[2];
  const float* b_mem1v = (const float*)d_in[3];
  const float* w_mem1o = (const float*)d_in[4];
  const float* b_mem1o = (const float*)d_in[5];
  const float* w_off = (const float*)d_in[6];
  const float* b_off = (const float*)d_in[7];
  const float* w_key = (const float*)d_in[8];
  const float* b_key = (const float*)d_in[9];
  const float* w_val = (const float*)d_in[10];
  const float* b_val = (const float*)d_in[11];
  const float* w_sk1 = (const float*)d_in[12];
  const float* b_sk1 = (const float*)d_in[13];
  const float* w_sk2 = (const float*)d_in[14];
  const float* b_sk2 = (const float*)d_in[15];
  const float* w_gate = (const float*)d_in[16];
  const float* b_gate = (const float*)d_in[17];
  const float* ln_g = (const float*)d_in[18];
  const float* ln_b = (const float*)d_in[19];
  const float* w_out = (const float*)d_in[20];
  const float* b_out = (const float*)d_in[21];
  float* out = (float*)d_out;
  float* ws = (float*)d_ws;

  const int BLP = B_ * L_ * P_;  // 262144
  const int BLD = B_ * L_ * D_;  // 2097152
  float* m1cT = ws;
  float* m1sT = m1cT + BLP;
  float* qc = m1sT + BLP;
  float* qs = qc + BLP;
  float* sg = qs + BLP;
  float* poff = sg + B_ * L_;
  float* ctxsum = poff + L_ * P_;              // B*64*256 = 65536 floats
  // Ybf (8192*384 shorts) and UT (B*NC*256*64 = 4.19M shorts) share a region
  short* Ybf = (short*)(ctxsum + B_ * 64 * 256);
  short* UT = Ybf;
  short* xbf = UT + (size_t)B_ * NC * 256 * 64;
  short* cbn = xbf;                   // aliases xbf (dead after gemm1)
  short* ctxbf = xbf + BLD;
  short* hs = ctxbf + BLD;
  short* gvT = hs + BLD;
  short* K2bf = gvT + BLD;            // B*L*64
  short* SPbf = K2bf + B_ * L_ * 64;  // B*L*64
  short* WA = SPbf + B_ * L_ * 64;
  short* W1 = WA + 384 * 256;
  short* WO = W1 + 256 * 512;
  short* W2T = WO + 256 * 256;
  short* W1OT = W2T + 32 * 256;

  wprep<<<3520, 256, 0, stream>>>(x, pos, w_val, w_mem1v, w_off, b_off, w_key, w_gate,
                                  w_sk1, w_out, w_sk2, w_mem1o, WA, W1, WO, W2T, W1OT,
                                  xbf, poff);
  gemm_k<2, 6, 0><<<128 * 6, 256, 0, stream>>>(xbf, nullptr, WA, nullptr, nullptr, nullptr, Ybf);
  kernelA3<<<(B_ * L_) / 8, 256, 0, stream>>>(Ybf, pos, poff, b_mem1v, b_key, b_gate, b_val,
                                              m1cT, m1sT, qc, qs, K2bf, gvT, sg);
  scan_all<<<516, 256, 0, stream>>>(m1cT, m1sT, sg, x, ctxsum);
  kernelCtx<<<256, 256, 0, stream>>>(x, ctxsum, ctxbf);
  gemm_k<4, 4, 1><<<128 * 4, 256, 0, stream>>>(xbf, ctxbf, W1, b_sk1, nullptr, nullptr, hs);
  kernelCD<<<(B_ * L_) / 64, 256, 0, stream>>>(hs, W2T, b_sk2, gvT, SPbf, UT);
  kernelE<<<256, 256, 0, stream>>>(UT);
  kernelFG<<<B_ * NC, 256, 0, stream>>>(UT, SPbf, K2bf, gvT, sg, m1cT, m1sT, qc, qs,
                                        W1OT, b_mem1o, ln_g, ln_b, cbn);
  gemm_k<2, 4, 2><<<128 * 4, 256, 0, stream>>>(cbn, nullptr, WO, b_out, x, out, nullptr);
}